// Round 1
// baseline (1317.409 us; speedup 1.0000x reference)
//
#include <hip/hip_runtime.h>
#include <math.h>

#define B 8
#define D 512
#define N 4096
#define HEADS 8
#define DH 64
#define HID 512
#define O3 1536
#define SCALE 0.125f
#define SQRT_D 22.62741699796952f

// ---------------------------------------------------------------------------
// K1/K6: tiled fp32 GEMM, C[b] = A[b] (Mx512) @ Bm[b] (512x4096) [+ bias]
// block 256 threads, 64x64 tile, BK=16, 4x4 micro-tile per thread
// ---------------------------------------------------------------------------
__global__ __launch_bounds__(256) void gemm512(const float* __restrict__ Aall, long long sA,
                                               const float* __restrict__ Ball, long long sB,
                                               float* __restrict__ Call, long long sC,
                                               const float* __restrict__ bias) {
    const int KDIM = 512;
    const int bz = blockIdx.z;
    const float* A = Aall + (size_t)bz * sA;
    const float* Bm = Ball + (size_t)bz * sB;
    float* C = Call + (size_t)bz * sC;

    __shared__ float As[16][68];  // [k][m], +4 pad keeps float4 reads aligned & stores ~2-way
    __shared__ float Bs[16][64];  // [k][n]

    const int tid = threadIdx.x;
    const int tx = tid & 15, ty = tid >> 4;
    const int row0 = blockIdx.y * 64;
    const int col0 = blockIdx.x * 64;
    // A load: each thread one float4: row ar, cols ac..ac+3
    const int ar = tid >> 2, ac = (tid & 3) << 2;
    // B load: each thread one float4: row br, cols bc..bc+3
    const int br = tid >> 4, bc = (tid & 15) << 2;

    float acc[4][4] = {};

    for (int k0 = 0; k0 < KDIM; k0 += 16) {
        float4 av = *(const float4*)(A + (size_t)(row0 + ar) * KDIM + k0 + ac);
        As[ac + 0][ar] = av.x;
        As[ac + 1][ar] = av.y;
        As[ac + 2][ar] = av.z;
        As[ac + 3][ar] = av.w;
        *(float4*)&Bs[br][bc] = *(const float4*)(Bm + (size_t)(k0 + br) * N + col0 + bc);
        __syncthreads();
#pragma unroll
        for (int kk = 0; kk < 16; ++kk) {
            float4 a4 = *(const float4*)&As[kk][ty << 2];
            float4 b4 = *(const float4*)&Bs[kk][tx << 2];
            float a[4] = {a4.x, a4.y, a4.z, a4.w};
            float b[4] = {b4.x, b4.y, b4.z, b4.w};
#pragma unroll
            for (int i = 0; i < 4; ++i)
#pragma unroll
                for (int j = 0; j < 4; ++j) acc[i][j] += a[i] * b[j];
        }
        __syncthreads();
    }

#pragma unroll
    for (int i = 0; i < 4; ++i) {
        int row = row0 + (ty << 2) + i;
        float bv = bias ? bias[row] : 0.f;
        float4 o4 = make_float4(acc[i][0] + bv, acc[i][1] + bv, acc[i][2] + bv, acc[i][3] + bv);
        *(float4*)(C + (size_t)row * N + col0 + (tx << 2)) = o4;
    }
}

// ---------------------------------------------------------------------------
// K2: softmax over d (64 rows within a head) for q, fold in SCALE. In place.
// One thread per (b,h,n) column; coalesced across n.
// ---------------------------------------------------------------------------
__global__ __launch_bounds__(256) void softmax_q(float* __restrict__ qkv) {
    const int n = blockIdx.x * 256 + threadIdx.x;
    const int h = blockIdx.y, b = blockIdx.z;
    float* base = qkv + ((size_t)b * O3 + h * DH) * (size_t)N + n;
    float v[DH];
    float m = -1e30f;
#pragma unroll
    for (int d = 0; d < DH; ++d) {
        v[d] = base[(size_t)d * N];
        m = fmaxf(m, v[d]);
    }
    float s = 0.f;
#pragma unroll
    for (int d = 0; d < DH; ++d) {
        v[d] = __expf(v[d] - m);
        s += v[d];
    }
    float r = SCALE / s;
#pragma unroll
    for (int d = 0; d < DH; ++d) base[(size_t)d * N] = v[d] * r;
}

// ---------------------------------------------------------------------------
// K3: softmax over n (4096) for k. One block (256 thr) per (b, row). In place.
// ---------------------------------------------------------------------------
__global__ __launch_bounds__(256) void softmax_k(float* __restrict__ qkv) {
    const int row = blockIdx.x;  // 0..511  (= h*64+d)
    const int b = blockIdx.y;
    float* base = qkv + ((size_t)b * O3 + HID + row) * (size_t)N;
    const int t = threadIdx.x;
    __shared__ float redm[4];
    __shared__ float reds[4];

    float v[16];
    float m = -1e30f;
#pragma unroll
    for (int i = 0; i < 16; ++i) {
        v[i] = base[i * 256 + t];
        m = fmaxf(m, v[i]);
    }
#pragma unroll
    for (int off = 32; off; off >>= 1) m = fmaxf(m, __shfl_xor(m, off));
    const int wid = t >> 6, lane = t & 63;
    if (lane == 0) redm[wid] = m;
    __syncthreads();
    m = fmaxf(fmaxf(redm[0], redm[1]), fmaxf(redm[2], redm[3]));

    float s = 0.f;
#pragma unroll
    for (int i = 0; i < 16; ++i) {
        v[i] = __expf(v[i] - m);
        s += v[i];
    }
#pragma unroll
    for (int off = 32; off; off >>= 1) s += __shfl_xor(s, off);
    if (lane == 0) reds[wid] = s;
    __syncthreads();
    s = reds[0] + reds[1] + reds[2] + reds[3];
    float r = 1.f / s;
#pragma unroll
    for (int i = 0; i < 16; ++i) base[i * 256 + t] = v[i] * r;
}

// ---------------------------------------------------------------------------
// K4: ctx[b,h,d,e] += sum_{n in chunk} k_sm[d,n] * v[e,n]   (atomicAdd accum)
// grid (8 chunks, HEADS, B), block 256, each thread a 4x4 (d,e) micro-tile
// ---------------------------------------------------------------------------
__global__ __launch_bounds__(256) void context_partial(const float* __restrict__ qkv,
                                                       float* __restrict__ ctx) {
    const int ch = blockIdx.x, h = blockIdx.y, b = blockIdx.z;
    const int CHUNK = N / 8;
    const float* kbase = qkv + ((size_t)b * O3 + HID + h * DH) * (size_t)N + ch * CHUNK;
    const float* vbase = qkv + ((size_t)b * O3 + 2 * HID + h * DH) * (size_t)N + ch * CHUNK;
    __shared__ float ks[64][33];
    __shared__ float vs[64][33];
    const int tid = threadIdx.x;
    const int d0 = (tid >> 4) << 2;
    const int e0 = (tid & 15) << 2;
    float acc[4][4] = {};

    for (int n0 = 0; n0 < CHUNK; n0 += 32) {
#pragma unroll
        for (int i = 0; i < 8; ++i) {
            int lin = tid + i * 256;
            int r = lin >> 5, c = lin & 31;
            ks[r][c] = kbase[(size_t)r * N + n0 + c];
            vs[r][c] = vbase[(size_t)r * N + n0 + c];
        }
        __syncthreads();
#pragma unroll 8
        for (int nn = 0; nn < 32; ++nn) {
            float kv[4], vv[4];
#pragma unroll
            for (int i = 0; i < 4; ++i) {
                kv[i] = ks[d0 + i][nn];
                vv[i] = vs[e0 + i][nn];
            }
#pragma unroll
            for (int i = 0; i < 4; ++i)
#pragma unroll
                for (int j = 0; j < 4; ++j) acc[i][j] += kv[i] * vv[j];
        }
        __syncthreads();
    }

    float* cbase = ctx + ((size_t)(b * HEADS + h)) * DH * DH;
#pragma unroll
    for (int i = 0; i < 4; ++i)
#pragma unroll
        for (int j = 0; j < 4; ++j) atomicAdd(&cbase[(d0 + i) * DH + (e0 + j)], acc[i][j]);
}

// ---------------------------------------------------------------------------
// K5: W2[b][o][h*64+d] = sum_e w_out[o][h*64+e] * ctx[b,h,d,e]
// grid (HEADS, B), block 256
// ---------------------------------------------------------------------------
__global__ __launch_bounds__(256) void fold_wout(const float* __restrict__ w_out,
                                                 const float* __restrict__ ctx,
                                                 float* __restrict__ w2) {
    const int h = blockIdx.x, b = blockIdx.y;
    __shared__ float cs[DH][DH + 1];
    __shared__ float wt[64][DH + 1];
    const int t = threadIdx.x;
    const float* cbase = ctx + ((size_t)(b * HEADS + h)) * DH * DH;
#pragma unroll
    for (int i = 0; i < 16; ++i) {
        int lin = t + i * 256;
        cs[lin >> 6][lin & 63] = cbase[lin];
    }
    __syncthreads();
    const int dd = t & 63;
    const int og = t >> 6;
    for (int o0 = 0; o0 < D; o0 += 64) {
#pragma unroll
        for (int i = 0; i < 16; ++i) {
            int lin = t + i * 256;
            int r = lin >> 6, c = lin & 63;
            wt[r][c] = w_out[(size_t)(o0 + r) * HID + h * DH + c];
        }
        __syncthreads();
#pragma unroll
        for (int i = 0; i < 16; ++i) {
            int orow = og * 16 + i;
            float acc = 0.f;
#pragma unroll
            for (int e = 0; e < DH; ++e) acc += wt[orow][e] * cs[dd][e];
            w2[((size_t)b * D + o0 + orow) * D + h * DH + dd] = acc;
        }
        __syncthreads();
    }
}

// ---------------------------------------------------------------------------
// K7: RMSNorm over channel dim (512) per (b,n), in place on d_out
// ---------------------------------------------------------------------------
__global__ __launch_bounds__(256) void rmsnorm(float* __restrict__ y, const float* __restrict__ g) {
    const int n = blockIdx.x * 256 + threadIdx.x;
    const int b = blockIdx.y;
    float* col = y + (size_t)b * D * N + n;
    float ss = 0.f;
    for (int o = 0; o < D; ++o) {
        float v = col[(size_t)o * N];
        ss += v * v;
    }
    float r = SQRT_D / fmaxf(sqrtf(ss), 1e-12f);
    for (int o = 0; o < D; ++o) {
        col[(size_t)o * N] = col[(size_t)o * N] * r * g[o];
    }
}

extern "C" void kernel_launch(void* const* d_in, const int* in_sizes, int n_in,
                              void* d_out, int out_size, void* d_ws, size_t ws_size,
                              hipStream_t stream) {
    const float* x = (const float*)d_in[0];       // [B, D, N]
    const float* w_qkv = (const float*)d_in[1];   // [1536, 512]
    const float* w_out = (const float*)d_in[2];   // [512, 512]
    const float* b_out = (const float*)d_in[3];   // [512]
    const float* g = (const float*)d_in[4];       // [512]
    float* out = (float*)d_out;                   // [B, D, N]

    float* qkv = (float*)d_ws;                               // B*O3*N floats (192 MB)
    float* ctx = qkv + (size_t)B * O3 * N;                   // B*H*64*64 floats (128 KB)
    float* w2 = ctx + (size_t)B * HEADS * DH * DH;           // B*D*D floats (8 MB)

    hipMemsetAsync(ctx, 0, (size_t)B * HEADS * DH * DH * sizeof(float), stream);

    // K1: qkv = w_qkv @ x  per batch
    gemm512<<<dim3(N / 64, O3 / 64, B), 256, 0, stream>>>(
        w_qkv, 0LL, x, (long long)D * N, qkv, (long long)O3 * N, nullptr);

    // K2/K3: softmaxes in place
    softmax_q<<<dim3(N / 256, HEADS, B), 256, 0, stream>>>(qkv);
    softmax_k<<<dim3(HID, B), 256, 0, stream>>>(qkv);

    // K4: context accumulate
    context_partial<<<dim3(8, HEADS, B), 256, 0, stream>>>(qkv, ctx);

    // K5: fold w_out with ctx -> per-batch 512x512 weight
    fold_wout<<<dim3(HEADS, B), 256, 0, stream>>>(w_out, ctx, w2);

    // K6: y = W2[b] @ q_sm + b_out  -> d_out
    gemm512<<<dim3(N / 64, D / 64, B), 256, 0, stream>>>(
        w2, (long long)D * D, qkv, (long long)O3 * N, out, (long long)D * N, b_out);

    // K7: RMSNorm in place
    rmsnorm<<<dim3(N / 256, B), 256, 0, stream>>>(out, g);
}

// Round 2
// 576.672 us; speedup vs baseline: 2.2845x; 2.2845x over previous
//
#include <hip/hip_runtime.h>
#include <math.h>

#define B 8
#define D 512
#define N 4096
#define HEADS 8
#define DH 64
#define HID 512
#define O3 1536
#define KDIM 512
#define SCALE 0.125f
#define SQRT_D 22.62741699796952f

typedef __attribute__((ext_vector_type(4))) float f32x4;
typedef __attribute__((ext_vector_type(8))) short bf16x8;

static __device__ __forceinline__ unsigned short f2bf(float f) {
    unsigned int u = __float_as_uint(f);
    unsigned int r = (u + 0x7fffu + ((u >> 16) & 1u)) >> 16;
    return (unsigned short)r;
}

static __device__ __forceinline__ void gload_lds16(const void* g, void* l) {
    __builtin_amdgcn_global_load_lds(
        (const __attribute__((address_space(1))) unsigned int*)g,
        (__attribute__((address_space(3))) unsigned int*)l, 16, 0, 0);
}

// ---------------------------------------------------------------------------
// cvt_w: w_qkv fp32 [1536*512] -> bf16
// ---------------------------------------------------------------------------
__global__ __launch_bounds__(256) void cvt_w(const float* __restrict__ w,
                                             unsigned short* __restrict__ wb) {
    int i = (blockIdx.x * 256 + threadIdx.x) * 4;
    float4 v = *(const float4*)(w + i);
    __align__(8) unsigned short o[4] = {f2bf(v.x), f2bf(v.y), f2bf(v.z), f2bf(v.w)};
    *(uint2*)(wb + i) = *(const uint2*)o;
}

// ---------------------------------------------------------------------------
// transpose_x: x fp32 [b][512][4096] -> xT bf16 [b][4096][512]
// 64x64 tiles via LDS
// ---------------------------------------------------------------------------
__global__ __launch_bounds__(256) void transpose_x(const float* __restrict__ x,
                                                   unsigned short* __restrict__ xT) {
    __shared__ float tile[64][65];
    const int n0 = blockIdx.x * 64, d0 = blockIdx.y * 64, b = blockIdx.z;
    const float* xb = x + (size_t)b * D * N;
    unsigned short* xTb = xT + (size_t)b * N * KDIM;
    const int t = threadIdx.x;
    const int r = t >> 4, c4 = (t & 15) * 4;
#pragma unroll
    for (int i = 0; i < 4; ++i) {
        int row = r + i * 16;
        float4 v = *(const float4*)(xb + (size_t)(d0 + row) * N + n0 + c4);
        tile[row][c4 + 0] = v.x;
        tile[row][c4 + 1] = v.y;
        tile[row][c4 + 2] = v.z;
        tile[row][c4 + 3] = v.w;
    }
    __syncthreads();
#pragma unroll
    for (int pass = 0; pass < 2; ++pass) {
        int orow = (t >> 3) + pass * 32;  // n within tile
        int oc = (t & 7) * 8;             // d within tile
        __align__(16) unsigned short o[8];
#pragma unroll
        for (int e = 0; e < 8; ++e) o[e] = f2bf(tile[oc + e][orow]);
        *(uint4*)(xTb + (size_t)(n0 + orow) * KDIM + d0 + oc) = *(const uint4*)o;
    }
}

// ---------------------------------------------------------------------------
// gemm_bt: C[b][m][n] = sum_k A[b][m][k] * BT[b][n][k]   (bf16 in, fp32 out)
// 128x128 tile, BK=64, 4 waves (2x2), mfma_f32_16x16x32_bf16
// LDS XOR-swizzle: 16B chunk index ^= (row&7); staged via global_load_lds
// with inverse-swizzled global source (linear LDS dest).
// ---------------------------------------------------------------------------
__global__ __launch_bounds__(256) void gemm_bt(const unsigned short* __restrict__ Aall, long long sA,
                                               const unsigned short* __restrict__ BTall, long long sBT,
                                               float* __restrict__ Call, long long sC) {
    const int b = blockIdx.z;
    const unsigned short* A = Aall + (size_t)b * sA;
    const unsigned short* BT = BTall + (size_t)b * sBT;
    float* C = Call + (size_t)b * sC;

    __shared__ __align__(16) unsigned short As[128 * 64];
    __shared__ __align__(16) unsigned short Bs[128 * 64];

    const int t = threadIdx.x;
    const int lane = t & 63;
    const int wid = t >> 6;
    const int wm = wid >> 1, wn = wid & 1;
    const int row0 = blockIdx.y * 128;
    const int col0 = blockIdx.x * 128;

    // staging geometry: issue i covers LDS bytes [i*4096 + t*16, +16)
    int prow[4], coff[4];
#pragma unroll
    for (int i = 0; i < 4; ++i) {
        int p = i * 4096 + t * 16;
        int pr = p >> 7;          // row in tile (128B rows = 64 bf16)
        int pc = (p >> 4) & 7;    // 16B chunk in row
        prow[i] = pr;
        coff[i] = (pc ^ (pr & 7)) * 8;  // element offset of logical chunk
    }

    // fragment read byte-offsets
    int aoff[4][2], boff[4][2];
#pragma unroll
    for (int m = 0; m < 4; ++m) {
        int arow = wm * 64 + m * 16 + (lane & 15);
        int brow = wn * 64 + m * 16 + (lane & 15);
#pragma unroll
        for (int s = 0; s < 2; ++s) {
            int chunk = s * 4 + (lane >> 4);
            aoff[m][s] = arow * 128 + ((chunk ^ (arow & 7)) << 4);
            boff[m][s] = brow * 128 + ((chunk ^ (brow & 7)) << 4);
        }
    }

    f32x4 acc[4][4] = {};

    for (int k0 = 0; k0 < KDIM; k0 += 64) {
#pragma unroll
        for (int i = 0; i < 4; ++i) {
            const unsigned short* ga = A + (size_t)(row0 + prow[i]) * KDIM + k0 + coff[i];
            gload_lds16(ga, (char*)As + i * 4096 + t * 16);
        }
#pragma unroll
        for (int i = 0; i < 4; ++i) {
            const unsigned short* gb = BT + (size_t)(col0 + prow[i]) * KDIM + k0 + coff[i];
            gload_lds16(gb, (char*)Bs + i * 4096 + t * 16);
        }
        __syncthreads();

        bf16x8 af[4][2], bfr[4][2];
#pragma unroll
        for (int m = 0; m < 4; ++m)
#pragma unroll
            for (int s = 0; s < 2; ++s) {
                af[m][s] = *(const bf16x8*)((const char*)As + aoff[m][s]);
                bfr[m][s] = *(const bf16x8*)((const char*)Bs + boff[m][s]);
            }
#pragma unroll
        for (int s = 0; s < 2; ++s)
#pragma unroll
            for (int m = 0; m < 4; ++m)
#pragma unroll
                for (int n = 0; n < 4; ++n)
                    acc[m][n] = __builtin_amdgcn_mfma_f32_16x16x32_bf16(af[m][s], bfr[n][s],
                                                                        acc[m][n], 0, 0, 0);
        __syncthreads();
    }

    // epilogue: C/D layout col=lane&15, row=4*(lane>>4)+r
#pragma unroll
    for (int m = 0; m < 4; ++m) {
        int row_b = row0 + wm * 64 + m * 16 + (lane >> 4) * 4;
#pragma unroll
        for (int n = 0; n < 4; ++n) {
            int col = col0 + wn * 64 + n * 16 + (lane & 15);
#pragma unroll
            for (int r = 0; r < 4; ++r)
                C[(size_t)(row_b + r) * N + col] = acc[m][n][r];
        }
    }
}

// ---------------------------------------------------------------------------
// softmax_q: reads q fp32 [b][512][4096] (in d_out scratch), softmax over d
// within each head, folds SCALE, writes qT bf16 [b][n][512]
// ---------------------------------------------------------------------------
__global__ __launch_bounds__(256) void softmax_q(const float* __restrict__ q,
                                                 unsigned short* __restrict__ qT) {
    const int n = blockIdx.x * 256 + threadIdx.x;
    const int h = blockIdx.y, b = blockIdx.z;
    const float* base = q + ((size_t)b * HID + h * DH) * (size_t)N + n;
    float v[DH];
    float m = -1e30f;
#pragma unroll
    for (int d = 0; d < DH; ++d) {
        v[d] = base[(size_t)d * N];
        m = fmaxf(m, v[d]);
    }
    float s = 0.f;
#pragma unroll
    for (int d = 0; d < DH; ++d) {
        v[d] = __expf(v[d] - m);
        s += v[d];
    }
    float r = SCALE / s;
    __align__(16) unsigned short o[DH];
#pragma unroll
    for (int d = 0; d < DH; ++d) o[d] = f2bf(v[d] * r);
    uint4* dst = (uint4*)(qT + ((size_t)b * N + n) * KDIM + h * DH);
#pragma unroll
    for (int i = 0; i < 8; ++i) dst[i] = ((const uint4*)o)[i];
}

// ---------------------------------------------------------------------------
// softmax_k: softmax over n (4096), in place on kv rows 0..511 per batch
// ---------------------------------------------------------------------------
__global__ __launch_bounds__(256) void softmax_k(float* __restrict__ kv) {
    const int row = blockIdx.x;  // 0..511
    const int b = blockIdx.y;
    float* base = kv + ((size_t)b * 1024 + row) * (size_t)N;
    const int t = threadIdx.x;
    __shared__ float redm[4];
    __shared__ float reds[4];

    float v[16];
    float m = -1e30f;
#pragma unroll
    for (int i = 0; i < 16; ++i) {
        v[i] = base[i * 256 + t];
        m = fmaxf(m, v[i]);
    }
#pragma unroll
    for (int off = 32; off; off >>= 1) m = fmaxf(m, __shfl_xor(m, off));
    const int wid = t >> 6, lane = t & 63;
    if (lane == 0) redm[wid] = m;
    __syncthreads();
    m = fmaxf(fmaxf(redm[0], redm[1]), fmaxf(redm[2], redm[3]));

    float s = 0.f;
#pragma unroll
    for (int i = 0; i < 16; ++i) {
        v[i] = __expf(v[i] - m);
        s += v[i];
    }
#pragma unroll
    for (int off = 32; off; off >>= 1) s += __shfl_xor(s, off);
    if (lane == 0) reds[wid] = s;
    __syncthreads();
    s = reds[0] + reds[1] + reds[2] + reds[3];
    float r = 1.f / s;
#pragma unroll
    for (int i = 0; i < 16; ++i) base[i * 256 + t] = v[i] * r;
}

// ---------------------------------------------------------------------------
// context_partial: ctx[b,h,d,e] += sum_{n chunk} k_sm[d,n]*v[e,n]
// ---------------------------------------------------------------------------
__global__ __launch_bounds__(256) void context_partial(const float* __restrict__ kv,
                                                       float* __restrict__ ctx) {
    const int ch = blockIdx.x, h = blockIdx.y, b = blockIdx.z;
    const int CHUNK = N / 8;
    const float* kbase = kv + ((size_t)b * 1024 + h * DH) * (size_t)N + ch * CHUNK;
    const float* vbase = kv + ((size_t)b * 1024 + 512 + h * DH) * (size_t)N + ch * CHUNK;
    __shared__ float ks[64][33];
    __shared__ float vs[64][33];
    const int tid = threadIdx.x;
    const int d0 = (tid >> 4) << 2;
    const int e0 = (tid & 15) << 2;
    float acc[4][4] = {};

    for (int n0 = 0; n0 < CHUNK; n0 += 32) {
#pragma unroll
        for (int i = 0; i < 8; ++i) {
            int lin = tid + i * 256;
            int r = lin >> 5, c = lin & 31;
            ks[r][c] = kbase[(size_t)r * N + n0 + c];
            vs[r][c] = vbase[(size_t)r * N + n0 + c];
        }
        __syncthreads();
#pragma unroll 8
        for (int nn = 0; nn < 32; ++nn) {
            float kvv[4], vv[4];
#pragma unroll
            for (int i = 0; i < 4; ++i) {
                kvv[i] = ks[d0 + i][nn];
                vv[i] = vs[e0 + i][nn];
            }
#pragma unroll
            for (int i = 0; i < 4; ++i)
#pragma unroll
                for (int j = 0; j < 4; ++j) acc[i][j] += kvv[i] * vv[j];
        }
        __syncthreads();
    }

    float* cbase = ctx + ((size_t)(b * HEADS + h)) * DH * DH;
#pragma unroll
    for (int i = 0; i < 4; ++i)
#pragma unroll
        for (int j = 0; j < 4; ++j) atomicAdd(&cbase[(d0 + i) * DH + (e0 + j)], acc[i][j]);
}

// ---------------------------------------------------------------------------
// fold_wout: W2[b][o][h*64+d] = sum_e w_out[o][h*64+e]*ctx[b,h,d,e] -> bf16
// ---------------------------------------------------------------------------
__global__ __launch_bounds__(256) void fold_wout(const float* __restrict__ w_out,
                                                 const float* __restrict__ ctx,
                                                 unsigned short* __restrict__ w2) {
    const int h = blockIdx.x, b = blockIdx.y;
    __shared__ float cs[DH][DH + 1];
    __shared__ float wt[64][DH + 1];
    const int t = threadIdx.x;
    const float* cbase = ctx + ((size_t)(b * HEADS + h)) * DH * DH;
#pragma unroll
    for (int i = 0; i < 16; ++i) {
        int lin = t + i * 256;
        cs[lin >> 6][lin & 63] = cbase[lin];
    }
    __syncthreads();
    const int dd = t & 63;
    const int og = t >> 6;
    for (int o0 = 0; o0 < D; o0 += 64) {
#pragma unroll
        for (int i = 0; i < 16; ++i) {
            int lin = t + i * 256;
            int r = lin >> 6, c = lin & 63;
            wt[r][c] = w_out[(size_t)(o0 + r) * HID + h * DH + c];
        }
        __syncthreads();
#pragma unroll
        for (int i = 0; i < 16; ++i) {
            int orow = og * 16 + i;
            float acc = 0.f;
#pragma unroll
            for (int e = 0; e < DH; ++e) acc += wt[orow][e] * cs[dd][e];
            w2[((size_t)b * D + o0 + orow) * D + h * DH + dd] = f2bf(acc);
        }
        __syncthreads();
    }
}

// ---------------------------------------------------------------------------
// rmsnorm with bias fold: y = (y + b_out) normalized over channels * g * sqrt(D)
// ---------------------------------------------------------------------------
__global__ __launch_bounds__(256) void rmsnorm(float* __restrict__ y,
                                               const float* __restrict__ b_out,
                                               const float* __restrict__ g) {
    const int n = blockIdx.x * 256 + threadIdx.x;
    const int b = blockIdx.y;
    float* col = y + (size_t)b * D * N + n;
    float ss = 0.f;
#pragma unroll 8
    for (int o = 0; o < D; ++o) {
        float v = col[(size_t)o * N] + b_out[o];
        ss += v * v;
    }
    float r = SQRT_D / fmaxf(sqrtf(ss), 1e-12f);
#pragma unroll 8
    for (int o = 0; o < D; ++o) {
        col[(size_t)o * N] = (col[(size_t)o * N] + b_out[o]) * r * g[o];
    }
}

extern "C" void kernel_launch(void* const* d_in, const int* in_sizes, int n_in,
                              void* d_out, int out_size, void* d_ws, size_t ws_size,
                              hipStream_t stream) {
    const float* x = (const float*)d_in[0];       // [B, D, N]
    const float* w_qkv = (const float*)d_in[1];   // [1536, 512]
    const float* w_out = (const float*)d_in[2];   // [512, 512]
    const float* b_out = (const float*)d_in[3];   // [512]
    const float* g = (const float*)d_in[4];       // [512]
    float* out = (float*)d_out;                   // [B, 512, 4096]

    // workspace layout
    float* kv = (float*)d_ws;                                   // B*1024*N fp32 (128 MB)
    float* ctx = kv + (size_t)B * 1024 * N;                     // B*H*64*64 fp32 (1 MB)
    unsigned short* w2 = (unsigned short*)(ctx + (size_t)B * HEADS * DH * DH);  // B*512*512 bf16 (4 MB)
    unsigned short* wqb = w2 + (size_t)B * D * D;               // 1536*512 bf16 (1.5 MB)
    unsigned short* xTqT = wqb + (size_t)O3 * KDIM;             // B*N*512 bf16 (32 MB), xT then qT

    hipMemsetAsync(ctx, 0, (size_t)B * HEADS * DH * DH * sizeof(float), stream);

    // converts
    cvt_w<<<dim3(O3 * KDIM / 1024), 256, 0, stream>>>(w_qkv, wqb);
    transpose_x<<<dim3(N / 64, D / 64, B), 256, 0, stream>>>(x, xTqT);

    // K1: qkv = w_qkv @ x ; q rows (0..511) -> d_out scratch, k/v rows -> kv
    gemm_bt<<<dim3(N / 128, 4, B), 256, 0, stream>>>(
        wqb, 0LL, xTqT, (long long)N * KDIM, out, (long long)HID * N);
    gemm_bt<<<dim3(N / 128, 8, B), 256, 0, stream>>>(
        wqb + (size_t)HID * KDIM, 0LL, xTqT, (long long)N * KDIM, kv, (long long)1024 * N);

    // softmaxes
    softmax_q<<<dim3(N / 256, HEADS, B), 256, 0, stream>>>(out, xTqT);  // qT overwrites xT
    softmax_k<<<dim3(HID, B), 256, 0, stream>>>(kv);

    // context + fold
    context_partial<<<dim3(8, HEADS, B), 256, 0, stream>>>(kv, ctx);
    fold_wout<<<dim3(HEADS, B), 256, 0, stream>>>(w_out, ctx, w2);

    // K6: y = W2[b] @ q_sm -> d_out
    gemm_bt<<<dim3(N / 128, D / 128, B), 256, 0, stream>>>(
        w2, (long long)D * D, xTqT, (long long)N * KDIM, out, (long long)D * N);

    // rmsnorm (+bias) in place
    rmsnorm<<<dim3(N / 256, B), 256, 0, stream>>>(out, b_out, g);
}

// Round 3
// 378.468 us; speedup vs baseline: 3.4809x; 1.5237x over previous
//
#include <hip/hip_runtime.h>
#include <math.h>

#define B 8
#define D 512
#define N 4096
#define HEADS 8
#define DH 64
#define HID 512
#define O3 1536
#define KDIM 512
#define SCALE 0.125f
#define SQRT_D 22.62741699796952f

typedef __attribute__((ext_vector_type(4))) float f32x4;
typedef __attribute__((ext_vector_type(8))) short bf16x8;

static __device__ __forceinline__ unsigned short f2bf(float f) {
    unsigned int u = __float_as_uint(f);
    unsigned int r = (u + 0x7fffu + ((u >> 16) & 1u)) >> 16;
    return (unsigned short)r;
}

static __device__ __forceinline__ void gload_lds16(const void* g, void* l) {
    __builtin_amdgcn_global_load_lds(
        (const __attribute__((address_space(1))) unsigned int*)g,
        (__attribute__((address_space(3))) unsigned int*)l, 16, 0, 0);
}

// ---------------------------------------------------------------------------
// cvt_w: w_qkv fp32 [1536*512] -> bf16
// ---------------------------------------------------------------------------
__global__ __launch_bounds__(256) void cvt_w(const float* __restrict__ w,
                                             unsigned short* __restrict__ wb) {
    int i = (blockIdx.x * 256 + threadIdx.x) * 4;
    float4 v = *(const float4*)(w + i);
    __align__(8) unsigned short o[4] = {f2bf(v.x), f2bf(v.y), f2bf(v.z), f2bf(v.w)};
    *(uint2*)(wb + i) = *(const uint2*)o;
}

// ---------------------------------------------------------------------------
// transpose_x: x fp32 [b][512][4096] -> xT bf16 [b][4096][512]
// ---------------------------------------------------------------------------
__global__ __launch_bounds__(256) void transpose_x(const float* __restrict__ x,
                                                   unsigned short* __restrict__ xT) {
    __shared__ float tile[64][65];
    const int n0 = blockIdx.x * 64, d0 = blockIdx.y * 64, b = blockIdx.z;
    const float* xb = x + (size_t)b * D * N;
    unsigned short* xTb = xT + (size_t)b * N * KDIM;
    const int t = threadIdx.x;
    const int r = t >> 4, c4 = (t & 15) * 4;
#pragma unroll
    for (int i = 0; i < 4; ++i) {
        int row = r + i * 16;
        float4 v = *(const float4*)(xb + (size_t)(d0 + row) * N + n0 + c4);
        tile[row][c4 + 0] = v.x;
        tile[row][c4 + 1] = v.y;
        tile[row][c4 + 2] = v.z;
        tile[row][c4 + 3] = v.w;
    }
    __syncthreads();
#pragma unroll
    for (int pass = 0; pass < 2; ++pass) {
        int orow = (t >> 3) + pass * 32;  // n within tile
        int oc = (t & 7) * 8;             // d within tile
        __align__(16) unsigned short o[8];
#pragma unroll
        for (int e = 0; e < 8; ++e) o[e] = f2bf(tile[oc + e][orow]);
        *(uint4*)(xTb + (size_t)(n0 + orow) * KDIM + d0 + oc) = *(const uint4*)o;
    }
}

// ---------------------------------------------------------------------------
// gemm_bt: C[b][m][n] = sum_k A[b][m][k] * BT[b][n][k]   (bf16 in, fp32 out)
// 128x128 tile, BK=64, 4 waves (2x2), mfma_f32_16x16x32_bf16
// ---------------------------------------------------------------------------
__global__ __launch_bounds__(256) void gemm_bt(const unsigned short* __restrict__ Aall, long long sA,
                                               const unsigned short* __restrict__ BTall, long long sBT,
                                               float* __restrict__ Call, long long sC) {
    const int b = blockIdx.z;
    const unsigned short* A = Aall + (size_t)b * sA;
    const unsigned short* BT = BTall + (size_t)b * sBT;
    float* C = Call + (size_t)b * sC;

    __shared__ __align__(16) unsigned short As[128 * 64];
    __shared__ __align__(16) unsigned short Bs[128 * 64];

    const int t = threadIdx.x;
    const int lane = t & 63;
    const int wid = t >> 6;
    const int wm = wid >> 1, wn = wid & 1;
    const int row0 = blockIdx.y * 128;
    const int col0 = blockIdx.x * 128;

    int prow[4], coff[4];
#pragma unroll
    for (int i = 0; i < 4; ++i) {
        int p = i * 4096 + t * 16;
        int pr = p >> 7;
        int pc = (p >> 4) & 7;
        prow[i] = pr;
        coff[i] = (pc ^ (pr & 7)) * 8;
    }

    int aoff[4][2], boff[4][2];
#pragma unroll
    for (int m = 0; m < 4; ++m) {
        int arow = wm * 64 + m * 16 + (lane & 15);
        int brow = wn * 64 + m * 16 + (lane & 15);
#pragma unroll
        for (int s = 0; s < 2; ++s) {
            int chunk = s * 4 + (lane >> 4);
            aoff[m][s] = arow * 128 + ((chunk ^ (arow & 7)) << 4);
            boff[m][s] = brow * 128 + ((chunk ^ (brow & 7)) << 4);
        }
    }

    f32x4 acc[4][4] = {};

    for (int k0 = 0; k0 < KDIM; k0 += 64) {
#pragma unroll
        for (int i = 0; i < 4; ++i)
            gload_lds16(A + (size_t)(row0 + prow[i]) * KDIM + k0 + coff[i],
                        (char*)As + i * 4096 + t * 16);
#pragma unroll
        for (int i = 0; i < 4; ++i)
            gload_lds16(BT + (size_t)(col0 + prow[i]) * KDIM + k0 + coff[i],
                        (char*)Bs + i * 4096 + t * 16);
        __syncthreads();

        bf16x8 af[4][2], bfr[4][2];
#pragma unroll
        for (int m = 0; m < 4; ++m)
#pragma unroll
            for (int s = 0; s < 2; ++s) {
                af[m][s] = *(const bf16x8*)((const char*)As + aoff[m][s]);
                bfr[m][s] = *(const bf16x8*)((const char*)Bs + boff[m][s]);
            }
#pragma unroll
        for (int s = 0; s < 2; ++s)
#pragma unroll
            for (int m = 0; m < 4; ++m)
#pragma unroll
                for (int n = 0; n < 4; ++n)
                    acc[m][n] = __builtin_amdgcn_mfma_f32_16x16x32_bf16(af[m][s], bfr[n][s],
                                                                        acc[m][n], 0, 0, 0);
        __syncthreads();
    }

#pragma unroll
    for (int m = 0; m < 4; ++m) {
        int row_b = row0 + wm * 64 + m * 16 + (lane >> 4) * 4;
#pragma unroll
        for (int n = 0; n < 4; ++n) {
            int col = col0 + wn * 64 + n * 16 + (lane & 15);
#pragma unroll
            for (int r = 0; r < 4; ++r)
                C[(size_t)(row_b + r) * N + col] = acc[m][n][r];
        }
    }
}

// ---------------------------------------------------------------------------
// gemm_q_sm: q = w_qkv[0:512] @ x, then softmax over d per head (wave-local),
// fold SCALE, emit qT bf16 [b][n][512]. Wave (wm,wn) holds head by*2+wm's
// full 64 rows for 64 columns -> d-softmax = 16 in-reg values + shfl g.
// ---------------------------------------------------------------------------
__global__ __launch_bounds__(256) void gemm_q_sm(const unsigned short* __restrict__ Aw,
                                                 const unsigned short* __restrict__ BTall,
                                                 unsigned short* __restrict__ qT) {
    const int b = blockIdx.z;
    const unsigned short* A = Aw;
    const unsigned short* BT = BTall + (size_t)b * N * KDIM;

    __shared__ __align__(16) unsigned short As[128 * 64];
    __shared__ __align__(16) unsigned short Bs[128 * 64];

    const int t = threadIdx.x;
    const int lane = t & 63;
    const int wid = t >> 6;
    const int wm = wid >> 1, wn = wid & 1;
    const int row0 = blockIdx.y * 128;
    const int col0 = blockIdx.x * 128;

    int prow[4], coff[4];
#pragma unroll
    for (int i = 0; i < 4; ++i) {
        int p = i * 4096 + t * 16;
        int pr = p >> 7;
        int pc = (p >> 4) & 7;
        prow[i] = pr;
        coff[i] = (pc ^ (pr & 7)) * 8;
    }

    int aoff[4][2], boff[4][2];
#pragma unroll
    for (int m = 0; m < 4; ++m) {
        int arow = wm * 64 + m * 16 + (lane & 15);
        int brow = wn * 64 + m * 16 + (lane & 15);
#pragma unroll
        for (int s = 0; s < 2; ++s) {
            int chunk = s * 4 + (lane >> 4);
            aoff[m][s] = arow * 128 + ((chunk ^ (arow & 7)) << 4);
            boff[m][s] = brow * 128 + ((chunk ^ (brow & 7)) << 4);
        }
    }

    f32x4 acc[4][4] = {};

    for (int k0 = 0; k0 < KDIM; k0 += 64) {
#pragma unroll
        for (int i = 0; i < 4; ++i)
            gload_lds16(A + (size_t)(row0 + prow[i]) * KDIM + k0 + coff[i],
                        (char*)As + i * 4096 + t * 16);
#pragma unroll
        for (int i = 0; i < 4; ++i)
            gload_lds16(BT + (size_t)(col0 + prow[i]) * KDIM + k0 + coff[i],
                        (char*)Bs + i * 4096 + t * 16);
        __syncthreads();

        bf16x8 af[4][2], bfr[4][2];
#pragma unroll
        for (int m = 0; m < 4; ++m)
#pragma unroll
            for (int s = 0; s < 2; ++s) {
                af[m][s] = *(const bf16x8*)((const char*)As + aoff[m][s]);
                bfr[m][s] = *(const bf16x8*)((const char*)Bs + boff[m][s]);
            }
#pragma unroll
        for (int s = 0; s < 2; ++s)
#pragma unroll
            for (int m = 0; m < 4; ++m)
#pragma unroll
                for (int n = 0; n < 4; ++n)
                    acc[m][n] = __builtin_amdgcn_mfma_f32_16x16x32_bf16(af[m][s], bfr[n][s],
                                                                        acc[m][n], 0, 0, 0);
        __syncthreads();
    }

    // epilogue: per column softmax over the wave's head (64 rows)
    const int h = blockIdx.y * 2 + wm;
    const int g = lane >> 4;
#pragma unroll
    for (int nf = 0; nf < 4; ++nf) {
        float mx = -1e30f;
#pragma unroll
        for (int m = 0; m < 4; ++m)
#pragma unroll
            for (int r = 0; r < 4; ++r) mx = fmaxf(mx, acc[m][nf][r]);
        mx = fmaxf(mx, __shfl_xor(mx, 16));
        mx = fmaxf(mx, __shfl_xor(mx, 32));
        float e[16];
        float s = 0.f;
#pragma unroll
        for (int m = 0; m < 4; ++m)
#pragma unroll
            for (int r = 0; r < 4; ++r) {
                e[m * 4 + r] = __expf(acc[m][nf][r] - mx);
                s += e[m * 4 + r];
            }
        s += __shfl_xor(s, 16);
        s += __shfl_xor(s, 32);
        float rs = SCALE / s;
        int n = col0 + wn * 64 + nf * 16 + (lane & 15);
        unsigned short* dst = qT + ((size_t)b * N + n) * KDIM + h * 64 + g * 4;
#pragma unroll
        for (int m = 0; m < 4; ++m) {
            __align__(8) unsigned short o4[4] = {f2bf(e[m * 4 + 0] * rs), f2bf(e[m * 4 + 1] * rs),
                                                 f2bf(e[m * 4 + 2] * rs), f2bf(e[m * 4 + 3] * rs)};
            *(uint2*)(dst + m * 16) = *(const uint2*)o4;
        }
    }
}

// ---------------------------------------------------------------------------
// kstat: per k-row max and 1/sum(exp) over n. One block per (row, b).
// ---------------------------------------------------------------------------
__global__ __launch_bounds__(256) void kstat(const float* __restrict__ kv,
                                             float2* __restrict__ st) {
    const int row = blockIdx.x;  // 0..511
    const int b = blockIdx.y;
    const float* base = kv + ((size_t)b * 1024 + row) * (size_t)N;
    const int t = threadIdx.x;
    __shared__ float redm[4];
    __shared__ float reds[4];

    float v[16];
    float m = -1e30f;
#pragma unroll
    for (int i = 0; i < 16; ++i) {
        v[i] = base[i * 256 + t];
        m = fmaxf(m, v[i]);
    }
#pragma unroll
    for (int off = 32; off; off >>= 1) m = fmaxf(m, __shfl_xor(m, off));
    const int wid = t >> 6, lane = t & 63;
    if (lane == 0) redm[wid] = m;
    __syncthreads();
    m = fmaxf(fmaxf(redm[0], redm[1]), fmaxf(redm[2], redm[3]));

    float s = 0.f;
#pragma unroll
    for (int i = 0; i < 16; ++i) s += __expf(v[i] - m);
#pragma unroll
    for (int off = 32; off; off >>= 1) s += __shfl_xor(s, off);
    if (lane == 0) reds[wid] = s;
    __syncthreads();
    if (t == 0) {
        s = reds[0] + reds[1] + reds[2] + reds[3];
        st[b * 512 + row] = make_float2(m, 1.f / s);
    }
}

// ---------------------------------------------------------------------------
// context_partial: ctx[b,h,d,e] += sum_{n chunk} softmax_k(k)[d,n]*v[e,n]
// k softmax applied on the fly from kstat.
// ---------------------------------------------------------------------------
__global__ __launch_bounds__(256) void context_partial(const float* __restrict__ kv,
                                                       const float2* __restrict__ st,
                                                       float* __restrict__ ctx) {
    const int ch = blockIdx.x, h = blockIdx.y, b = blockIdx.z;
    const int CHUNK = N / 8;
    const float* kbase = kv + ((size_t)b * 1024 + h * DH) * (size_t)N + ch * CHUNK;
    const float* vbase = kv + ((size_t)b * 1024 + 512 + h * DH) * (size_t)N + ch * CHUNK;
    __shared__ float ks[64][33];
    __shared__ float vs[64][33];
    __shared__ float msh[64], ish[64];
    const int tid = threadIdx.x;
    if (tid < 64) {
        float2 v = st[b * 512 + h * DH + tid];
        msh[tid] = v.x;
        ish[tid] = v.y;
    }
    __syncthreads();
    const int d0 = (tid >> 4) << 2;
    const int e0 = (tid & 15) << 2;
    float acc[4][4] = {};

    for (int n0 = 0; n0 < CHUNK; n0 += 32) {
#pragma unroll
        for (int i = 0; i < 8; ++i) {
            int lin = tid + i * 256;
            int r = lin >> 5, c = lin & 31;
            ks[r][c] = __expf(kbase[(size_t)r * N + n0 + c] - msh[r]) * ish[r];
            vs[r][c] = vbase[(size_t)r * N + n0 + c];
        }
        __syncthreads();
#pragma unroll 8
        for (int nn = 0; nn < 32; ++nn) {
            float kvv[4], vv[4];
#pragma unroll
            for (int i = 0; i < 4; ++i) {
                kvv[i] = ks[d0 + i][nn];
                vv[i] = vs[e0 + i][nn];
            }
#pragma unroll
            for (int i = 0; i < 4; ++i)
#pragma unroll
                for (int j = 0; j < 4; ++j) acc[i][j] += kvv[i] * vv[j];
        }
        __syncthreads();
    }

    float* cbase = ctx + ((size_t)(b * HEADS + h)) * DH * DH;
#pragma unroll
    for (int i = 0; i < 4; ++i)
#pragma unroll
        for (int j = 0; j < 4; ++j) atomicAdd(&cbase[(d0 + i) * DH + (e0 + j)], acc[i][j]);
}

// ---------------------------------------------------------------------------
// fold_wout2: W2[(b*D+o)*D + h*64+d] = dot64(w_out[o][h*64:], ctx[b,h,d,:])
// one output per thread, 8192 blocks
// ---------------------------------------------------------------------------
__global__ __launch_bounds__(256) void fold_wout2(const float* __restrict__ w_out,
                                                  const float* __restrict__ ctx,
                                                  unsigned short* __restrict__ w2) {
    const int idx = blockIdx.x * 256 + threadIdx.x;  // 0 .. B*D*D-1
    const int b = idx >> 18;
    const int rem = idx & 0x3FFFF;
    const int o = rem >> 9;
    const int hd = rem & 511;
    const int h = hd >> 6, d = hd & 63;
    const float* wrow = w_out + (size_t)o * HID + h * 64;
    const float* crow = ctx + (((size_t)(b * HEADS + h)) * DH + d) * DH;
    float a0 = 0.f, a1 = 0.f, a2 = 0.f, a3 = 0.f;
#pragma unroll
    for (int e = 0; e < DH; e += 4) {
        float4 w4 = *(const float4*)(wrow + e);
        float4 c4 = *(const float4*)(crow + e);
        a0 += w4.x * c4.x;
        a1 += w4.y * c4.y;
        a2 += w4.z * c4.z;
        a3 += w4.w * c4.w;
    }
    w2[idx] = f2bf((a0 + a1) + (a2 + a3));
}

// ---------------------------------------------------------------------------
// rmsnorm with bias fold
// ---------------------------------------------------------------------------
__global__ __launch_bounds__(256) void rmsnorm(float* __restrict__ y,
                                               const float* __restrict__ b_out,
                                               const float* __restrict__ g) {
    const int n = blockIdx.x * 256 + threadIdx.x;
    const int b = blockIdx.y;
    float* col = y + (size_t)b * D * N + n;
    float ss = 0.f;
#pragma unroll 8
    for (int o = 0; o < D; ++o) {
        float v = col[(size_t)o * N] + b_out[o];
        ss += v * v;
    }
    float r = SQRT_D / fmaxf(sqrtf(ss), 1e-12f);
#pragma unroll 8
    for (int o = 0; o < D; ++o) {
        col[(size_t)o * N] = (col[(size_t)o * N] + b_out[o]) * r * g[o];
    }
}

extern "C" void kernel_launch(void* const* d_in, const int* in_sizes, int n_in,
                              void* d_out, int out_size, void* d_ws, size_t ws_size,
                              hipStream_t stream) {
    const float* x = (const float*)d_in[0];
    const float* w_qkv = (const float*)d_in[1];
    const float* w_out = (const float*)d_in[2];
    const float* b_out = (const float*)d_in[3];
    const float* g = (const float*)d_in[4];
    float* out = (float*)d_out;

    // workspace layout
    float* kv = (float*)d_ws;                                   // B*1024*N fp32 (128 MB)
    float* ctx = kv + (size_t)B * 1024 * N;                     // 1 MB
    unsigned short* w2 = (unsigned short*)(ctx + (size_t)B * HEADS * DH * DH);  // 4 MB
    unsigned short* wqb = w2 + (size_t)B * D * D;               // 1.5 MB
    unsigned short* xT = wqb + (size_t)O3 * KDIM;               // B*N*512 bf16 (32 MB)
    unsigned short* qT = xT + (size_t)B * N * KDIM;             // B*N*512 bf16 (32 MB)
    float2* kst = (float2*)(qT + (size_t)B * N * KDIM);         // 32 KB

    hipMemsetAsync(ctx, 0, (size_t)B * HEADS * DH * DH * sizeof(float), stream);

    cvt_w<<<dim3(O3 * KDIM / 1024), 256, 0, stream>>>(w_qkv, wqb);
    transpose_x<<<dim3(N / 64, D / 64, B), 256, 0, stream>>>(x, xT);

    // q GEMM with fused softmax_q -> qT bf16
    gemm_q_sm<<<dim3(N / 128, HID / 128, B), 256, 0, stream>>>(wqb, xT, qT);

    // k,v GEMM -> kv fp32
    gemm_bt<<<dim3(N / 128, 8, B), 256, 0, stream>>>(
        wqb + (size_t)HID * KDIM, 0LL, xT, (long long)N * KDIM, kv, (long long)1024 * N);

    // k softmax stats + context + fold
    kstat<<<dim3(HID, B), 256, 0, stream>>>(kv, kst);
    context_partial<<<dim3(8, HEADS, B), 256, 0, stream>>>(kv, kst, ctx);
    fold_wout2<<<dim3(B * D * D / 256), 256, 0, stream>>>(w_out, ctx, w2);

    // final GEMM: y = W2[b] @ q_smT -> d_out
    gemm_bt<<<dim3(N / 128, D / 128, B), 256, 0, stream>>>(
        w2, (long long)D * D, qT, (long long)N * KDIM, out, (long long)D * N);

    rmsnorm<<<dim3(N / 256, B), 256, 0, stream>>>(out, b_out, g);
}

// Round 4
// 310.328 us; speedup vs baseline: 4.2452x; 1.2196x over previous
//
#include <hip/hip_runtime.h>
#include <math.h>

#define B 8
#define D 512
#define N 4096
#define HEADS 8
#define DH 64
#define HID 512
#define O3 1536
#define KDIM 512
#define SCALE 0.125f
#define SQRT_D 22.62741699796952f

typedef __attribute__((ext_vector_type(4))) float f32x4;
typedef __attribute__((ext_vector_type(8))) short bf16x8;

static __device__ __forceinline__ unsigned short f2bf(float f) {
    unsigned int u = __float_as_uint(f);
    unsigned int r = (u + 0x7fffu + ((u >> 16) & 1u)) >> 16;
    return (unsigned short)r;
}

static __device__ __forceinline__ float bf2f(unsigned short u) {
    return __uint_as_float((unsigned int)u << 16);
}

static __device__ __forceinline__ void gload_lds16(const void* g, void* l) {
    __builtin_amdgcn_global_load_lds(
        (const __attribute__((address_space(1))) unsigned int*)g,
        (__attribute__((address_space(3))) unsigned int*)l, 16, 0, 0);
}

// ---------------------------------------------------------------------------
// cvt_w: w_qkv fp32 [1536*512] -> bf16
// ---------------------------------------------------------------------------
__global__ __launch_bounds__(256) void cvt_w(const float* __restrict__ w,
                                             unsigned short* __restrict__ wb) {
    int i = (blockIdx.x * 256 + threadIdx.x) * 4;
    float4 v = *(const float4*)(w + i);
    __align__(8) unsigned short o[4] = {f2bf(v.x), f2bf(v.y), f2bf(v.z), f2bf(v.w)};
    *(uint2*)(wb + i) = *(const uint2*)o;
}

// ---------------------------------------------------------------------------
// transpose_x: x fp32 [b][512][4096] -> xT bf16 [b][4096][512]
// ---------------------------------------------------------------------------
__global__ __launch_bounds__(256) void transpose_x(const float* __restrict__ x,
                                                   unsigned short* __restrict__ xT) {
    __shared__ float tile[64][65];
    const int n0 = blockIdx.x * 64, d0 = blockIdx.y * 64, b = blockIdx.z;
    const float* xb = x + (size_t)b * D * N;
    unsigned short* xTb = xT + (size_t)b * N * KDIM;
    const int t = threadIdx.x;
    const int r = t >> 4, c4 = (t & 15) * 4;
#pragma unroll
    for (int i = 0; i < 4; ++i) {
        int row = r + i * 16;
        float4 v = *(const float4*)(xb + (size_t)(d0 + row) * N + n0 + c4);
        tile[row][c4 + 0] = v.x;
        tile[row][c4 + 1] = v.y;
        tile[row][c4 + 2] = v.z;
        tile[row][c4 + 3] = v.w;
    }
    __syncthreads();
#pragma unroll
    for (int pass = 0; pass < 2; ++pass) {
        int orow = (t >> 3) + pass * 32;
        int oc = (t & 7) * 8;
        __align__(16) unsigned short o[8];
#pragma unroll
        for (int e = 0; e < 8; ++e) o[e] = f2bf(tile[oc + e][orow]);
        *(uint4*)(xTb + (size_t)(n0 + orow) * KDIM + d0 + oc) = *(const uint4*)o;
    }
}

// ---------------------------------------------------------------------------
// shared GEMM core: 128x128 tile, BK=64, 4 waves, mfma_f32_16x16x32_bf16
// ---------------------------------------------------------------------------
#define GEMM_CORE(A_PTR, BT_PTR, ACC)                                              \
    __shared__ __align__(16) unsigned short As[128 * 64];                          \
    __shared__ __align__(16) unsigned short Bs[128 * 64];                          \
    const int t = threadIdx.x;                                                     \
    const int lane = t & 63;                                                       \
    const int wid = t >> 6;                                                        \
    const int wm = wid >> 1, wn = wid & 1;                                         \
    int prow[4], coff[4];                                                          \
    _Pragma("unroll") for (int i = 0; i < 4; ++i) {                                \
        int p = i * 4096 + t * 16;                                                 \
        int pr = p >> 7;                                                           \
        int pc = (p >> 4) & 7;                                                     \
        prow[i] = pr;                                                              \
        coff[i] = (pc ^ (pr & 7)) * 8;                                             \
    }                                                                              \
    int aoff[4][2], boff[4][2];                                                    \
    _Pragma("unroll") for (int m = 0; m < 4; ++m) {                                \
        int arow = wm * 64 + m * 16 + (lane & 15);                                 \
        int brow = wn * 64 + m * 16 + (lane & 15);                                 \
        _Pragma("unroll") for (int s = 0; s < 2; ++s) {                            \
            int chunk = s * 4 + (lane >> 4);                                       \
            aoff[m][s] = arow * 128 + ((chunk ^ (arow & 7)) << 4);                 \
            boff[m][s] = brow * 128 + ((chunk ^ (brow & 7)) << 4);                 \
        }                                                                          \
    }                                                                              \
    f32x4 ACC[4][4] = {};                                                          \
    for (int k0 = 0; k0 < KDIM; k0 += 64) {                                        \
        _Pragma("unroll") for (int i = 0; i < 4; ++i)                              \
            gload_lds16(A_PTR + (size_t)(row0 + prow[i]) * KDIM + k0 + coff[i],    \
                        (char*)As + i * 4096 + t * 16);                            \
        _Pragma("unroll") for (int i = 0; i < 4; ++i)                              \
            gload_lds16(BT_PTR + (size_t)(col0 + prow[i]) * KDIM + k0 + coff[i],   \
                        (char*)Bs + i * 4096 + t * 16);                            \
        __syncthreads();                                                           \
        bf16x8 af[4][2], bfr[4][2];                                                \
        _Pragma("unroll") for (int m = 0; m < 4; ++m)                              \
            _Pragma("unroll") for (int s = 0; s < 2; ++s) {                        \
                af[m][s] = *(const bf16x8*)((const char*)As + aoff[m][s]);         \
                bfr[m][s] = *(const bf16x8*)((const char*)Bs + boff[m][s]);        \
            }                                                                      \
        _Pragma("unroll") for (int s = 0; s < 2; ++s)                              \
            _Pragma("unroll") for (int m = 0; m < 4; ++m)                          \
                _Pragma("unroll") for (int n = 0; n < 4; ++n)                      \
                    ACC[m][n] = __builtin_amdgcn_mfma_f32_16x16x32_bf16(           \
                        af[m][s], bfr[n][s], ACC[m][n], 0, 0, 0);                  \
        __syncthreads();                                                           \
    }

// ---------------------------------------------------------------------------
// gemm_bt: fp32 output (final projection)
// ---------------------------------------------------------------------------
__global__ __launch_bounds__(256) void gemm_bt(const unsigned short* __restrict__ Aall, long long sA,
                                               const unsigned short* __restrict__ BTall, long long sBT,
                                               float* __restrict__ Call, long long sC) {
    const int b = blockIdx.z;
    const unsigned short* A = Aall + (size_t)b * sA;
    const unsigned short* BT = BTall + (size_t)b * sBT;
    float* C = Call + (size_t)b * sC;
    const int row0 = blockIdx.y * 128;
    const int col0 = blockIdx.x * 128;
    GEMM_CORE(A, BT, acc)
#pragma unroll
    for (int m = 0; m < 4; ++m) {
        int row_b = row0 + wm * 64 + m * 16 + (lane >> 4) * 4;
#pragma unroll
        for (int n = 0; n < 4; ++n) {
            int col = col0 + wn * 64 + n * 16 + (lane & 15);
#pragma unroll
            for (int r = 0; r < 4; ++r)
                C[(size_t)(row_b + r) * N + col] = acc[m][n][r];
        }
    }
}

// ---------------------------------------------------------------------------
// gemm_kv: k,v = w_qkv[512:1536] @ x -> bf16 kvb [b][1024][N]
// ---------------------------------------------------------------------------
__global__ __launch_bounds__(256) void gemm_kv(const unsigned short* __restrict__ Aw,
                                               const unsigned short* __restrict__ BTall,
                                               unsigned short* __restrict__ kvall) {
    const int b = blockIdx.z;
    const unsigned short* A = Aw;
    const unsigned short* BT = BTall + (size_t)b * N * KDIM;
    unsigned short* C = kvall + (size_t)b * 1024 * N;
    const int row0 = blockIdx.y * 128;
    const int col0 = blockIdx.x * 128;
    GEMM_CORE(A, BT, acc)
#pragma unroll
    for (int m = 0; m < 4; ++m) {
        int row_b = row0 + wm * 64 + m * 16 + (lane >> 4) * 4;
#pragma unroll
        for (int n = 0; n < 4; ++n) {
            int col = col0 + wn * 64 + n * 16 + (lane & 15);
#pragma unroll
            for (int r = 0; r < 4; ++r)
                C[(size_t)(row_b + r) * N + col] = f2bf(acc[m][n][r]);
        }
    }
}

// ---------------------------------------------------------------------------
// gemm_q_sm: q GEMM + fused softmax over d per head -> qT bf16 [b][n][512]
// ---------------------------------------------------------------------------
__global__ __launch_bounds__(256) void gemm_q_sm(const unsigned short* __restrict__ Aw,
                                                 const unsigned short* __restrict__ BTall,
                                                 unsigned short* __restrict__ qT) {
    const int b = blockIdx.z;
    const unsigned short* A = Aw;
    const unsigned short* BT = BTall + (size_t)b * N * KDIM;
    const int row0 = blockIdx.y * 128;
    const int col0 = blockIdx.x * 128;
    GEMM_CORE(A, BT, acc)
    const int h = blockIdx.y * 2 + wm;
    const int g = lane >> 4;
#pragma unroll
    for (int nf = 0; nf < 4; ++nf) {
        float mx = -1e30f;
#pragma unroll
        for (int m = 0; m < 4; ++m)
#pragma unroll
            for (int r = 0; r < 4; ++r) mx = fmaxf(mx, acc[m][nf][r]);
        mx = fmaxf(mx, __shfl_xor(mx, 16));
        mx = fmaxf(mx, __shfl_xor(mx, 32));
        float e[16];
        float s = 0.f;
#pragma unroll
        for (int m = 0; m < 4; ++m)
#pragma unroll
            for (int r = 0; r < 4; ++r) {
                e[m * 4 + r] = __expf(acc[m][nf][r] - mx);
                s += e[m * 4 + r];
            }
        s += __shfl_xor(s, 16);
        s += __shfl_xor(s, 32);
        float rs = SCALE / s;
        int n = col0 + wn * 64 + nf * 16 + (lane & 15);
        unsigned short* dst = qT + ((size_t)b * N + n) * KDIM + h * 64 + g * 4;
#pragma unroll
        for (int m = 0; m < 4; ++m) {
            __align__(8) unsigned short o4[4] = {f2bf(e[m * 4 + 0] * rs), f2bf(e[m * 4 + 1] * rs),
                                                 f2bf(e[m * 4 + 2] * rs), f2bf(e[m * 4 + 3] * rs)};
            *(uint2*)(dst + m * 16) = *(const uint2*)o4;
        }
    }
}

// ---------------------------------------------------------------------------
// kstat: per k-row max and 1/sum(exp) over n (bf16 input)
// ---------------------------------------------------------------------------
__global__ __launch_bounds__(256) void kstat(const unsigned short* __restrict__ kvb,
                                             float2* __restrict__ st) {
    const int row = blockIdx.x;
    const int b = blockIdx.y;
    const unsigned short* base = kvb + ((size_t)b * 1024 + row) * (size_t)N;
    const int t = threadIdx.x;
    __shared__ float redm[4];
    __shared__ float reds[4];

    __align__(16) unsigned short raw[16];
    *(uint4*)raw = *(const uint4*)(base + t * 16);
    *(uint4*)(raw + 8) = *(const uint4*)(base + t * 16 + 8);
    float v[16];
    float m = -1e30f;
#pragma unroll
    for (int i = 0; i < 16; ++i) {
        v[i] = bf2f(raw[i]);
        m = fmaxf(m, v[i]);
    }
#pragma unroll
    for (int off = 32; off; off >>= 1) m = fmaxf(m, __shfl_xor(m, off));
    const int wid = t >> 6, lane = t & 63;
    if (lane == 0) redm[wid] = m;
    __syncthreads();
    m = fmaxf(fmaxf(redm[0], redm[1]), fmaxf(redm[2], redm[3]));

    float s = 0.f;
#pragma unroll
    for (int i = 0; i < 16; ++i) s += __expf(v[i] - m);
#pragma unroll
    for (int off = 32; off; off >>= 1) s += __shfl_xor(s, off);
    if (lane == 0) reds[wid] = s;
    __syncthreads();
    if (t == 0) {
        s = reds[0] + reds[1] + reds[2] + reds[3];
        st[b * 512 + row] = make_float2(m, 1.f / s);
    }
}

// ---------------------------------------------------------------------------
// context_partial: ctx[b,h,d,e] += sum_{n chunk} softmax_k(k)[d,n]*v[e,n]
// bf16 k,v input; softmax applied during staging.
// ---------------------------------------------------------------------------
__global__ __launch_bounds__(256) void context_partial(const unsigned short* __restrict__ kvb,
                                                       const float2* __restrict__ st,
                                                       float* __restrict__ ctx) {
    const int ch = blockIdx.x, h = blockIdx.y, b = blockIdx.z;
    const int CHUNK = N / 8;
    const unsigned short* kbase = kvb + ((size_t)b * 1024 + h * DH) * (size_t)N + ch * CHUNK;
    const unsigned short* vbase = kvb + ((size_t)b * 1024 + 512 + h * DH) * (size_t)N + ch * CHUNK;
    __shared__ float ks[64][33];
    __shared__ float vs[64][33];
    __shared__ float msh[64], ish[64];
    const int tid = threadIdx.x;
    if (tid < 64) {
        float2 v = st[b * 512 + h * DH + tid];
        msh[tid] = v.x;
        ish[tid] = v.y;
    }
    __syncthreads();
    const int d0 = (tid >> 4) << 2;
    const int e0 = (tid & 15) << 2;
    const int sr = tid >> 3;        // staging row 0..31
    const int sc = (tid & 7) * 4;   // staging col group
    float acc[4][4] = {};

    for (int n0 = 0; n0 < CHUNK; n0 += 32) {
#pragma unroll
        for (int half = 0; half < 2; ++half) {
            int r = sr + half * 32;
            __align__(8) unsigned short k4[4], v4[4];
            *(uint2*)k4 = *(const uint2*)(kbase + (size_t)r * N + n0 + sc);
            *(uint2*)v4 = *(const uint2*)(vbase + (size_t)r * N + n0 + sc);
            float mr = msh[r], ir = ish[r];
#pragma unroll
            for (int j = 0; j < 4; ++j) {
                ks[r][sc + j] = __expf(bf2f(k4[j]) - mr) * ir;
                vs[r][sc + j] = bf2f(v4[j]);
            }
        }
        __syncthreads();
#pragma unroll 8
        for (int nn = 0; nn < 32; ++nn) {
            float kvv[4], vv[4];
#pragma unroll
            for (int i = 0; i < 4; ++i) {
                kvv[i] = ks[d0 + i][nn];
                vv[i] = vs[e0 + i][nn];
            }
#pragma unroll
            for (int i = 0; i < 4; ++i)
#pragma unroll
                for (int j = 0; j < 4; ++j) acc[i][j] += kvv[i] * vv[j];
        }
        __syncthreads();
    }

    float* cbase = ctx + ((size_t)(b * HEADS + h)) * DH * DH;
#pragma unroll
    for (int i = 0; i < 4; ++i)
#pragma unroll
        for (int j = 0; j < 4; ++j) atomicAdd(&cbase[(d0 + i) * DH + (e0 + j)], acc[i][j]);
}

// ---------------------------------------------------------------------------
// fold_wout2: W2[(b*D+o)*D + h*64+d] = dot64(w_out[o][h*64:], ctx[b,h,d,:])
// ---------------------------------------------------------------------------
__global__ __launch_bounds__(256) void fold_wout2(const float* __restrict__ w_out,
                                                  const float* __restrict__ ctx,
                                                  unsigned short* __restrict__ w2) {
    const int idx = blockIdx.x * 256 + threadIdx.x;
    const int b = idx >> 18;
    const int rem = idx & 0x3FFFF;
    const int o = rem >> 9;
    const int hd = rem & 511;
    const int h = hd >> 6, d = hd & 63;
    const float* wrow = w_out + (size_t)o * HID + h * 64;
    const float* crow = ctx + (((size_t)(b * HEADS + h)) * DH + d) * DH;
    float a0 = 0.f, a1 = 0.f, a2 = 0.f, a3 = 0.f;
#pragma unroll
    for (int e = 0; e < DH; e += 4) {
        float4 w4 = *(const float4*)(wrow + e);
        float4 c4 = *(const float4*)(crow + e);
        a0 += w4.x * c4.x;
        a1 += w4.y * c4.y;
        a2 += w4.z * c4.z;
        a3 += w4.w * c4.w;
    }
    w2[idx] = f2bf((a0 + a1) + (a2 + a3));
}

// ---------------------------------------------------------------------------
// rmsnorm2: 64-column x 512-row tile per block, grid (N/64, B) = 512 blocks
// ---------------------------------------------------------------------------
__global__ __launch_bounds__(256) void rmsnorm2(float* __restrict__ y,
                                                const float* __restrict__ b_out,
                                                const float* __restrict__ g) {
    const int b = blockIdx.y;
    const int n0 = blockIdx.x * 64;
    float* base = y + (size_t)b * D * N + n0;
    __shared__ float bsh[D], gsh[D];
    __shared__ float4 red[4][16];
    const int t = threadIdx.x;
    bsh[t] = b_out[t];
    bsh[t + 256] = b_out[t + 256];
    gsh[t] = g[t];
    gsh[t + 256] = g[t + 256];
    __syncthreads();

    const int cg = t & 15;   // column group: cols cg*4..cg*4+3
    const int rg = t >> 4;   // row group 0..15

    float4 ss = make_float4(0.f, 0.f, 0.f, 0.f);
#pragma unroll 8
    for (int i = 0; i < 32; ++i) {
        int o = rg + i * 16;
        float4 v = *(const float4*)(base + (size_t)o * N + cg * 4);
        float bo = bsh[o];
        v.x += bo; v.y += bo; v.z += bo; v.w += bo;
        ss.x += v.x * v.x;
        ss.y += v.y * v.y;
        ss.z += v.z * v.z;
        ss.w += v.w * v.w;
    }
    ss.x += __shfl_xor(ss.x, 16); ss.y += __shfl_xor(ss.y, 16);
    ss.z += __shfl_xor(ss.z, 16); ss.w += __shfl_xor(ss.w, 16);
    ss.x += __shfl_xor(ss.x, 32); ss.y += __shfl_xor(ss.y, 32);
    ss.z += __shfl_xor(ss.z, 32); ss.w += __shfl_xor(ss.w, 32);
    const int wave = t >> 6, lane = t & 63;
    if (lane < 16) red[wave][lane] = ss;
    __syncthreads();
    float4 s0 = red[0][cg], s1 = red[1][cg], s2 = red[2][cg], s3 = red[3][cg];
    float4 tot = make_float4(s0.x + s1.x + s2.x + s3.x, s0.y + s1.y + s2.y + s3.y,
                             s0.z + s1.z + s2.z + s3.z, s0.w + s1.w + s2.w + s3.w);
    float4 rinv;
    rinv.x = SQRT_D / fmaxf(sqrtf(tot.x), 1e-12f);
    rinv.y = SQRT_D / fmaxf(sqrtf(tot.y), 1e-12f);
    rinv.z = SQRT_D / fmaxf(sqrtf(tot.z), 1e-12f);
    rinv.w = SQRT_D / fmaxf(sqrtf(tot.w), 1e-12f);

#pragma unroll 8
    for (int i = 0; i < 32; ++i) {
        int o = rg + i * 16;
        float4 v = *(const float4*)(base + (size_t)o * N + cg * 4);
        float bo = bsh[o], go = gsh[o];
        v.x = (v.x + bo) * rinv.x * go;
        v.y = (v.y + bo) * rinv.y * go;
        v.z = (v.z + bo) * rinv.z * go;
        v.w = (v.w + bo) * rinv.w * go;
        *(float4*)(base + (size_t)o * N + cg * 4) = v;
    }
}

extern "C" void kernel_launch(void* const* d_in, const int* in_sizes, int n_in,
                              void* d_out, int out_size, void* d_ws, size_t ws_size,
                              hipStream_t stream) {
    const float* x = (const float*)d_in[0];
    const float* w_qkv = (const float*)d_in[1];
    const float* w_out = (const float*)d_in[2];
    const float* b_out = (const float*)d_in[3];
    const float* g = (const float*)d_in[4];
    float* out = (float*)d_out;

    // workspace layout
    unsigned short* kvb = (unsigned short*)d_ws;                // B*1024*N bf16 (64 MB)
    float* ctx = (float*)(kvb + (size_t)B * 1024 * N);          // 1 MB
    unsigned short* w2 = (unsigned short*)(ctx + (size_t)B * HEADS * DH * DH);  // 4 MB
    unsigned short* wqb = w2 + (size_t)B * D * D;               // 1.5 MB
    unsigned short* xT = wqb + (size_t)O3 * KDIM;               // 32 MB
    unsigned short* qT = xT + (size_t)B * N * KDIM;             // 32 MB
    float2* kst = (float2*)(qT + (size_t)B * N * KDIM);         // 32 KB

    hipMemsetAsync(ctx, 0, (size_t)B * HEADS * DH * DH * sizeof(float), stream);

    cvt_w<<<dim3(O3 * KDIM / 1024), 256, 0, stream>>>(w_qkv, wqb);
    transpose_x<<<dim3(N / 64, D / 64, B), 256, 0, stream>>>(x, xT);

    gemm_q_sm<<<dim3(N / 128, HID / 128, B), 256, 0, stream>>>(wqb, xT, qT);
    gemm_kv<<<dim3(N / 128, 8, B), 256, 0, stream>>>(wqb + (size_t)HID * KDIM, xT, kvb);

    kstat<<<dim3(HID, B), 256, 0, stream>>>(kvb, kst);
    context_partial<<<dim3(8, HEADS, B), 256, 0, stream>>>(kvb, kst, ctx);
    fold_wout2<<<dim3(B * D * D / 256), 256, 0, stream>>>(w_out, ctx, w2);

    gemm_bt<<<dim3(N / 128, D / 128, B), 256, 0, stream>>>(
        w2, (long long)D * D, qT, (long long)N * KDIM, out, (long long)D * N);

    rmsnorm2<<<dim3(N / 64, B), 256, 0, stream>>>(out, b_out, g);
}

// Round 5
// 242.094 us; speedup vs baseline: 5.4417x; 1.2819x over previous
//
#include <hip/hip_runtime.h>
#include <math.h>

#define B 8
#define D 512
#define N 4096
#define HEADS 8
#define DH 64
#define HID 512
#define O3 1536
#define KDIM 512
#define SCALE 0.125f
#define SQRT_D 22.62741699796952f

typedef __attribute__((ext_vector_type(4))) float f32x4;
typedef __attribute__((ext_vector_type(8))) short bf16x8;

static __device__ __forceinline__ unsigned short f2bf(float f) {
    unsigned int u = __float_as_uint(f);
    unsigned int r = (u + 0x7fffu + ((u >> 16) & 1u)) >> 16;
    return (unsigned short)r;
}

static __device__ __forceinline__ float bf2f(unsigned short u) {
    return __uint_as_float((unsigned int)u << 16);
}

static __device__ __forceinline__ void gload_lds16(const void* g, void* l) {
    __builtin_amdgcn_global_load_lds(
        (const __attribute__((address_space(1))) unsigned int*)g,
        (__attribute__((address_space(3))) unsigned int*)l, 16, 0, 0);
}

// ---------------------------------------------------------------------------
// cvt_w: w_qkv fp32 [1536*512] -> bf16
// ---------------------------------------------------------------------------
__global__ __launch_bounds__(256) void cvt_w(const float* __restrict__ w,
                                             unsigned short* __restrict__ wb) {
    int i = (blockIdx.x * 256 + threadIdx.x) * 4;
    float4 v = *(const float4*)(w + i);
    __align__(8) unsigned short o[4] = {f2bf(v.x), f2bf(v.y), f2bf(v.z), f2bf(v.w)};
    *(uint2*)(wb + i) = *(const uint2*)o;
}

// ---------------------------------------------------------------------------
// transpose_x: x fp32 [b][512][4096] -> xT bf16 [b][4096][512]
// ---------------------------------------------------------------------------
__global__ __launch_bounds__(256) void transpose_x(const float* __restrict__ x,
                                                   unsigned short* __restrict__ xT) {
    __shared__ float tile[64][65];
    const int n0 = blockIdx.x * 64, d0 = blockIdx.y * 64, b = blockIdx.z;
    const float* xb = x + (size_t)b * D * N;
    unsigned short* xTb = xT + (size_t)b * N * KDIM;
    const int t = threadIdx.x;
    const int r = t >> 4, c4 = (t & 15) * 4;
#pragma unroll
    for (int i = 0; i < 4; ++i) {
        int row = r + i * 16;
        float4 v = *(const float4*)(xb + (size_t)(d0 + row) * N + n0 + c4);
        tile[row][c4 + 0] = v.x;
        tile[row][c4 + 1] = v.y;
        tile[row][c4 + 2] = v.z;
        tile[row][c4 + 3] = v.w;
    }
    __syncthreads();
#pragma unroll
    for (int pass = 0; pass < 2; ++pass) {
        int orow = (t >> 3) + pass * 32;
        int oc = (t & 7) * 8;
        __align__(16) unsigned short o[8];
#pragma unroll
        for (int e = 0; e < 8; ++e) o[e] = f2bf(tile[oc + e][orow]);
        *(uint4*)(xTb + (size_t)(n0 + orow) * KDIM + d0 + oc) = *(const uint4*)o;
    }
}

// ---------------------------------------------------------------------------
// shared GEMM core: 128x128 tile, BK=64, 4 waves, mfma_f32_16x16x32_bf16
// ---------------------------------------------------------------------------
#define GEMM_CORE(A_PTR, BT_PTR, ACC)                                              \
    __shared__ __align__(16) unsigned short As[128 * 64];                          \
    __shared__ __align__(16) unsigned short Bs[128 * 64];                          \
    const int t = threadIdx.x;                                                     \
    const int lane = t & 63;                                                       \
    const int wid = t >> 6;                                                        \
    const int wm = wid >> 1, wn = wid & 1;                                         \
    int prow[4], coff[4];                                                          \
    _Pragma("unroll") for (int i = 0; i < 4; ++i) {                                \
        int p = i * 4096 + t * 16;                                                 \
        int pr = p >> 7;                                                           \
        int pc = (p >> 4) & 7;                                                     \
        prow[i] = pr;                                                              \
        coff[i] = (pc ^ (pr & 7)) * 8;                                             \
    }                                                                              \
    int aoff[4][2], boff[4][2];                                                    \
    _Pragma("unroll") for (int m = 0; m < 4; ++m) {                                \
        int arow = wm * 64 + m * 16 + (lane & 15);                                 \
        int brow = wn * 64 + m * 16 + (lane & 15);                                 \
        _Pragma("unroll") for (int s = 0; s < 2; ++s) {                            \
            int chunk = s * 4 + (lane >> 4);                                       \
            aoff[m][s] = arow * 128 + ((chunk ^ (arow & 7)) << 4);                 \
            boff[m][s] = brow * 128 + ((chunk ^ (brow & 7)) << 4);                 \
        }                                                                          \
    }                                                                              \
    f32x4 ACC[4][4] = {};                                                          \
    for (int k0 = 0; k0 < KDIM; k0 += 64) {                                        \
        _Pragma("unroll") for (int i = 0; i < 4; ++i)                              \
            gload_lds16(A_PTR + (size_t)(row0 + prow[i]) * KDIM + k0 + coff[i],    \
                        (char*)As + i * 4096 + t * 16);                            \
        _Pragma("unroll") for (int i = 0; i < 4; ++i)                              \
            gload_lds16(BT_PTR + (size_t)(col0 + prow[i]) * KDIM + k0 + coff[i],   \
                        (char*)Bs + i * 4096 + t * 16);                            \
        __syncthreads();                                                           \
        bf16x8 af[4][2], bfr[4][2];                                                \
        _Pragma("unroll") for (int m = 0; m < 4; ++m)                              \
            _Pragma("unroll") for (int s = 0; s < 2; ++s) {                        \
                af[m][s] = *(const bf16x8*)((const char*)As + aoff[m][s]);         \
                bfr[m][s] = *(const bf16x8*)((const char*)Bs + boff[m][s]);        \
            }                                                                      \
        _Pragma("unroll") for (int s = 0; s < 2; ++s)                              \
            _Pragma("unroll") for (int m = 0; m < 4; ++m)                          \
                _Pragma("unroll") for (int n = 0; n < 4; ++n)                      \
                    ACC[m][n] = __builtin_amdgcn_mfma_f32_16x16x32_bf16(           \
                        af[m][s], bfr[n][s], ACC[m][n], 0, 0, 0);                  \
        __syncthreads();                                                           \
    }

// ---------------------------------------------------------------------------
// gemm_bt: fp32 output (final projection)
// ---------------------------------------------------------------------------
__global__ __launch_bounds__(256) void gemm_bt(const unsigned short* __restrict__ Aall, long long sA,
                                               const unsigned short* __restrict__ BTall, long long sBT,
                                               float* __restrict__ Call, long long sC) {
    const int b = blockIdx.z;
    const unsigned short* A = Aall + (size_t)b * sA;
    const unsigned short* BT = BTall + (size_t)b * sBT;
    float* C = Call + (size_t)b * sC;
    const int row0 = blockIdx.y * 128;
    const int col0 = blockIdx.x * 128;
    GEMM_CORE(A, BT, acc)
#pragma unroll
    for (int m = 0; m < 4; ++m) {
        int row_b = row0 + wm * 64 + m * 16 + (lane >> 4) * 4;
#pragma unroll
        for (int n = 0; n < 4; ++n) {
            int col = col0 + wn * 64 + n * 16 + (lane & 15);
#pragma unroll
            for (int r = 0; r < 4; ++r)
                C[(size_t)(row_b + r) * N + col] = acc[m][n][r];
        }
    }
}

// ---------------------------------------------------------------------------
// gemm_kv: k,v = w_qkv[512:1536] @ x -> bf16 kvb [b][1024][N]
// ---------------------------------------------------------------------------
__global__ __launch_bounds__(256) void gemm_kv(const unsigned short* __restrict__ Aw,
                                               const unsigned short* __restrict__ BTall,
                                               unsigned short* __restrict__ kvall) {
    const int b = blockIdx.z;
    const unsigned short* A = Aw;
    const unsigned short* BT = BTall + (size_t)b * N * KDIM;
    unsigned short* C = kvall + (size_t)b * 1024 * N;
    const int row0 = blockIdx.y * 128;
    const int col0 = blockIdx.x * 128;
    GEMM_CORE(A, BT, acc)
#pragma unroll
    for (int m = 0; m < 4; ++m) {
        int row_b = row0 + wm * 64 + m * 16 + (lane >> 4) * 4;
#pragma unroll
        for (int n = 0; n < 4; ++n) {
            int col = col0 + wn * 64 + n * 16 + (lane & 15);
#pragma unroll
            for (int r = 0; r < 4; ++r)
                C[(size_t)(row_b + r) * N + col] = f2bf(acc[m][n][r]);
        }
    }
}

// ---------------------------------------------------------------------------
// gemm_q_sm: q GEMM + fused softmax over d per head -> qT bf16 [b][n][512]
// ---------------------------------------------------------------------------
__global__ __launch_bounds__(256) void gemm_q_sm(const unsigned short* __restrict__ Aw,
                                                 const unsigned short* __restrict__ BTall,
                                                 unsigned short* __restrict__ qT) {
    const int b = blockIdx.z;
    const unsigned short* A = Aw;
    const unsigned short* BT = BTall + (size_t)b * N * KDIM;
    const int row0 = blockIdx.y * 128;
    const int col0 = blockIdx.x * 128;
    GEMM_CORE(A, BT, acc)
    const int h = blockIdx.y * 2 + wm;
    const int g = lane >> 4;
#pragma unroll
    for (int nf = 0; nf < 4; ++nf) {
        float mx = -1e30f;
#pragma unroll
        for (int m = 0; m < 4; ++m)
#pragma unroll
            for (int r = 0; r < 4; ++r) mx = fmaxf(mx, acc[m][nf][r]);
        mx = fmaxf(mx, __shfl_xor(mx, 16));
        mx = fmaxf(mx, __shfl_xor(mx, 32));
        float e[16];
        float s = 0.f;
#pragma unroll
        for (int m = 0; m < 4; ++m)
#pragma unroll
            for (int r = 0; r < 4; ++r) {
                e[m * 4 + r] = __expf(acc[m][nf][r] - mx);
                s += e[m * 4 + r];
            }
        s += __shfl_xor(s, 16);
        s += __shfl_xor(s, 32);
        float rs = SCALE / s;
        int n = col0 + wn * 64 + nf * 16 + (lane & 15);
        unsigned short* dst = qT + ((size_t)b * N + n) * KDIM + h * 64 + g * 4;
#pragma unroll
        for (int m = 0; m < 4; ++m) {
            __align__(8) unsigned short o4[4] = {f2bf(e[m * 4 + 0] * rs), f2bf(e[m * 4 + 1] * rs),
                                                 f2bf(e[m * 4 + 2] * rs), f2bf(e[m * 4 + 3] * rs)};
            *(uint2*)(dst + m * 16) = *(const uint2*)o4;
        }
    }
}

// ---------------------------------------------------------------------------
// kstat: per k-row max and 1/sum(exp) over n (bf16 input)
// ---------------------------------------------------------------------------
__global__ __launch_bounds__(256) void kstat(const unsigned short* __restrict__ kvb,
                                             float2* __restrict__ st) {
    const int row = blockIdx.x;
    const int b = blockIdx.y;
    const unsigned short* base = kvb + ((size_t)b * 1024 + row) * (size_t)N;
    const int t = threadIdx.x;
    __shared__ float redm[4];
    __shared__ float reds[4];

    __align__(16) unsigned short raw[16];
    *(uint4*)raw = *(const uint4*)(base + t * 16);
    *(uint4*)(raw + 8) = *(const uint4*)(base + t * 16 + 8);
    float v[16];
    float m = -1e30f;
#pragma unroll
    for (int i = 0; i < 16; ++i) {
        v[i] = bf2f(raw[i]);
        m = fmaxf(m, v[i]);
    }
#pragma unroll
    for (int off = 32; off; off >>= 1) m = fmaxf(m, __shfl_xor(m, off));
    const int wid = t >> 6, lane = t & 63;
    if (lane == 0) redm[wid] = m;
    __syncthreads();
    m = fmaxf(fmaxf(redm[0], redm[1]), fmaxf(redm[2], redm[3]));

    float s = 0.f;
#pragma unroll
    for (int i = 0; i < 16; ++i) s += __expf(v[i] - m);
#pragma unroll
    for (int off = 32; off; off >>= 1) s += __shfl_xor(s, off);
    if (lane == 0) reds[wid] = s;
    __syncthreads();
    if (t == 0) {
        s = reds[0] + reds[1] + reds[2] + reds[3];
        st[b * 512 + row] = make_float2(m, 1.f / s);
    }
}

// ---------------------------------------------------------------------------
// context_partial: ctx[b,h,d,e] += sum_{n chunk} softmax_k(k)[d,n]*v[e,n]
// ---------------------------------------------------------------------------
__global__ __launch_bounds__(256) void context_partial(const unsigned short* __restrict__ kvb,
                                                       const float2* __restrict__ st,
                                                       float* __restrict__ ctx) {
    const int ch = blockIdx.x, h = blockIdx.y, b = blockIdx.z;
    const int CHUNK = N / 8;
    const unsigned short* kbase = kvb + ((size_t)b * 1024 + h * DH) * (size_t)N + ch * CHUNK;
    const unsigned short* vbase = kvb + ((size_t)b * 1024 + 512 + h * DH) * (size_t)N + ch * CHUNK;
    __shared__ float ks[64][33];
    __shared__ float vs[64][33];
    __shared__ float msh[64], ish[64];
    const int tid = threadIdx.x;
    if (tid < 64) {
        float2 v = st[b * 512 + h * DH + tid];
        msh[tid] = v.x;
        ish[tid] = v.y;
    }
    __syncthreads();
    const int d0 = (tid >> 4) << 2;
    const int e0 = (tid & 15) << 2;
    const int sr = tid >> 3;
    const int sc = (tid & 7) * 4;
    float acc[4][4] = {};

    for (int n0 = 0; n0 < CHUNK; n0 += 32) {
#pragma unroll
        for (int half = 0; half < 2; ++half) {
            int r = sr + half * 32;
            __align__(8) unsigned short k4[4], v4[4];
            *(uint2*)k4 = *(const uint2*)(kbase + (size_t)r * N + n0 + sc);
            *(uint2*)v4 = *(const uint2*)(vbase + (size_t)r * N + n0 + sc);
            float mr = msh[r], ir = ish[r];
#pragma unroll
            for (int j = 0; j < 4; ++j) {
                ks[r][sc + j] = __expf(bf2f(k4[j]) - mr) * ir;
                vs[r][sc + j] = bf2f(v4[j]);
            }
        }
        __syncthreads();
#pragma unroll 8
        for (int nn = 0; nn < 32; ++nn) {
            float kvv[4], vv[4];
#pragma unroll
            for (int i = 0; i < 4; ++i) {
                kvv[i] = ks[d0 + i][nn];
                vv[i] = vs[e0 + i][nn];
            }
#pragma unroll
            for (int i = 0; i < 4; ++i)
#pragma unroll
                for (int j = 0; j < 4; ++j) acc[i][j] += kvv[i] * vv[j];
        }
        __syncthreads();
    }

    float* cbase = ctx + ((size_t)(b * HEADS + h)) * DH * DH;
#pragma unroll
    for (int i = 0; i < 4; ++i)
#pragma unroll
        for (int j = 0; j < 4; ++j) atomicAdd(&cbase[(d0 + i) * DH + (e0 + j)], acc[i][j]);
}

// ---------------------------------------------------------------------------
// fold_wout3: MFMA fold. Per (b,h): W2-slice[o][d] = sum_e w_out[o][h*64+e] *
// ctx[b,h,d,e].  M=512 (split in 4 o-tiles of 128), N=64, K=64.
// Stage both operands to LDS as bf16 with XOR swizzle (write & read sides).
// ---------------------------------------------------------------------------
__global__ __launch_bounds__(256) void fold_wout3(const float* __restrict__ w_out,
                                                  const float* __restrict__ ctx,
                                                  unsigned short* __restrict__ w2) {
    const int ot = blockIdx.x, h = blockIdx.y, b = blockIdx.z;
    __shared__ __align__(16) unsigned short As[128 * 64];
    __shared__ __align__(16) unsigned short Bs[64 * 64];
    const int t = threadIdx.x;
    const int lane = t & 63;
    const int wv = t >> 6;

    // stage A: w_out rows ot*128..+128, cols h*64..+64, fp32->bf16, swizzled
#pragma unroll
    for (int i = 0; i < 8; ++i) {
        int lin = t + i * 256;
        int r = lin >> 4;
        int c4 = (lin & 15) * 4;
        float4 v = *(const float4*)(w_out + (size_t)(ot * 128 + r) * HID + h * 64 + c4);
        __align__(8) unsigned short o4[4] = {f2bf(v.x), f2bf(v.y), f2bf(v.z), f2bf(v.w)};
        int chunk = c4 >> 3;
        int off = (c4 & 7) * 2;
        *(uint2*)((char*)As + r * 128 + ((chunk ^ (r & 7)) << 4) + off) = *(const uint2*)o4;
    }
    // stage B: ctx[b,h] 64x64
    const float* cb = ctx + ((size_t)(b * HEADS + h)) * DH * DH;
#pragma unroll
    for (int i = 0; i < 4; ++i) {
        int lin = t + i * 256;
        int r = lin >> 4;
        int c4 = (lin & 15) * 4;
        float4 v = *(const float4*)(cb + (size_t)r * DH + c4);
        __align__(8) unsigned short o4[4] = {f2bf(v.x), f2bf(v.y), f2bf(v.z), f2bf(v.w)};
        int chunk = c4 >> 3;
        int off = (c4 & 7) * 2;
        *(uint2*)((char*)Bs + r * 128 + ((chunk ^ (r & 7)) << 4) + off) = *(const uint2*)o4;
    }
    __syncthreads();

    f32x4 acc[2][4] = {};
#pragma unroll
    for (int s = 0; s < 2; ++s) {
        int chunk = s * 4 + (lane >> 4);
        bf16x8 bf[4];
#pragma unroll
        for (int nf = 0; nf < 4; ++nf) {
            int brow = nf * 16 + (lane & 15);
            bf[nf] = *(const bf16x8*)((const char*)Bs + brow * 128 + ((chunk ^ (brow & 7)) << 4));
        }
#pragma unroll
        for (int mm = 0; mm < 2; ++mm) {
            int arow = (wv * 2 + mm) * 16 + (lane & 15);
            bf16x8 a = *(const bf16x8*)((const char*)As + arow * 128 + ((chunk ^ (arow & 7)) << 4));
#pragma unroll
            for (int nf = 0; nf < 4; ++nf)
                acc[mm][nf] = __builtin_amdgcn_mfma_f32_16x16x32_bf16(a, bf[nf], acc[mm][nf], 0, 0, 0);
        }
    }

#pragma unroll
    for (int mm = 0; mm < 2; ++mm) {
        int o_base = ot * 128 + (wv * 2 + mm) * 16 + (lane >> 4) * 4;
#pragma unroll
        for (int nf = 0; nf < 4; ++nf) {
            int d = nf * 16 + (lane & 15);
#pragma unroll
            for (int rr = 0; rr < 4; ++rr)
                w2[((size_t)(b * D) + o_base + rr) * D + h * 64 + d] = f2bf(acc[mm][nf][rr]);
        }
    }
}

// ---------------------------------------------------------------------------
// rmsnorm2: 64-column x 512-row tile per block, grid (N/64, B) = 512 blocks
// ---------------------------------------------------------------------------
__global__ __launch_bounds__(256) void rmsnorm2(float* __restrict__ y,
                                                const float* __restrict__ b_out,
                                                const float* __restrict__ g) {
    const int b = blockIdx.y;
    const int n0 = blockIdx.x * 64;
    float* base = y + (size_t)b * D * N + n0;
    __shared__ float bsh[D], gsh[D];
    __shared__ float4 red[4][16];
    const int t = threadIdx.x;
    bsh[t] = b_out[t];
    bsh[t + 256] = b_out[t + 256];
    gsh[t] = g[t];
    gsh[t + 256] = g[t + 256];
    __syncthreads();

    const int cg = t & 15;
    const int rg = t >> 4;

    float4 ss = make_float4(0.f, 0.f, 0.f, 0.f);
#pragma unroll 8
    for (int i = 0; i < 32; ++i) {
        int o = rg + i * 16;
        float4 v = *(const float4*)(base + (size_t)o * N + cg * 4);
        float bo = bsh[o];
        v.x += bo; v.y += bo; v.z += bo; v.w += bo;
        ss.x += v.x * v.x;
        ss.y += v.y * v.y;
        ss.z += v.z * v.z;
        ss.w += v.w * v.w;
    }
    ss.x += __shfl_xor(ss.x, 16); ss.y += __shfl_xor(ss.y, 16);
    ss.z += __shfl_xor(ss.z, 16); ss.w += __shfl_xor(ss.w, 16);
    ss.x += __shfl_xor(ss.x, 32); ss.y += __shfl_xor(ss.y, 32);
    ss.z += __shfl_xor(ss.z, 32); ss.w += __shfl_xor(ss.w, 32);
    const int wave = t >> 6, lane = t & 63;
    if (lane < 16) red[wave][lane] = ss;
    __syncthreads();
    float4 s0 = red[0][cg], s1 = red[1][cg], s2 = red[2][cg], s3 = red[3][cg];
    float4 tot = make_float4(s0.x + s1.x + s2.x + s3.x, s0.y + s1.y + s2.y + s3.y,
                             s0.z + s1.z + s2.z + s3.z, s0.w + s1.w + s2.w + s3.w);
    float4 rinv;
    rinv.x = SQRT_D / fmaxf(sqrtf(tot.x), 1e-12f);
    rinv.y = SQRT_D / fmaxf(sqrtf(tot.y), 1e-12f);
    rinv.z = SQRT_D / fmaxf(sqrtf(tot.z), 1e-12f);
    rinv.w = SQRT_D / fmaxf(sqrtf(tot.w), 1e-12f);

#pragma unroll 8
    for (int i = 0; i < 32; ++i) {
        int o = rg + i * 16;
        float4 v = *(const float4*)(base + (size_t)o * N + cg * 4);
        float bo = bsh[o], go = gsh[o];
        v.x = (v.x + bo) * rinv.x * go;
        v.y = (v.y + bo) * rinv.y * go;
        v.z = (v.z + bo) * rinv.z * go;
        v.w = (v.w + bo) * rinv.w * go;
        *(float4*)(base + (size_t)o * N + cg * 4) = v;
    }
}

extern "C" void kernel_launch(void* const* d_in, const int* in_sizes, int n_in,
                              void* d_out, int out_size, void* d_ws, size_t ws_size,
                              hipStream_t stream) {
    const float* x = (const float*)d_in[0];
    const float* w_qkv = (const float*)d_in[1];
    const float* w_out = (const float*)d_in[2];
    const float* b_out = (const float*)d_in[3];
    const float* g = (const float*)d_in[4];
    float* out = (float*)d_out;

    // workspace layout
    unsigned short* kvb = (unsigned short*)d_ws;                // B*1024*N bf16 (64 MB)
    float* ctx = (float*)(kvb + (size_t)B * 1024 * N);          // 1 MB
    unsigned short* w2 = (unsigned short*)(ctx + (size_t)B * HEADS * DH * DH);  // 4 MB
    unsigned short* wqb = w2 + (size_t)B * D * D;               // 1.5 MB
    unsigned short* xT = wqb + (size_t)O3 * KDIM;               // 32 MB
    unsigned short* qT = xT + (size_t)B * N * KDIM;             // 32 MB
    float2* kst = (float2*)(qT + (size_t)B * N * KDIM);         // 32 KB

    hipMemsetAsync(ctx, 0, (size_t)B * HEADS * DH * DH * sizeof(float), stream);

    cvt_w<<<dim3(O3 * KDIM / 1024), 256, 0, stream>>>(w_qkv, wqb);
    transpose_x<<<dim3(N / 64, D / 64, B), 256, 0, stream>>>(x, xT);

    gemm_q_sm<<<dim3(N / 128, HID / 128, B), 256, 0, stream>>>(wqb, xT, qT);
    gemm_kv<<<dim3(N / 128, 8, B), 256, 0, stream>>>(wqb + (size_t)HID * KDIM, xT, kvb);

    kstat<<<dim3(HID, B), 256, 0, stream>>>(kvb, kst);
    context_partial<<<dim3(8, HEADS, B), 256, 0, stream>>>(kvb, kst, ctx);
    fold_wout3<<<dim3(4, HEADS, B), 256, 0, stream>>>(w_out, ctx, w2);

    gemm_bt<<<dim3(N / 128, D / 128, B), 256, 0, stream>>>(
        w2, (long long)D * D, qT, (long long)N * KDIM, out, (long long)D * N);

    rmsnorm2<<<dim3(N / 64, B), 256, 0, stream>>>(out, b_out, g);
}

// Round 6
// 187.695 us; speedup vs baseline: 7.0189x; 1.2898x over previous
//
#include <hip/hip_runtime.h>
#include <math.h>

#define B 8
#define D 512
#define N 4096
#define HEADS 8
#define DH 64
#define HID 512
#define O3 1536
#define KDIM 512
#define SCALE 0.125f
#define SQRT_D 22.62741699796952f

typedef __attribute__((ext_vector_type(4))) float f32x4;
typedef __attribute__((ext_vector_type(8))) short bf16x8;

static __device__ __forceinline__ unsigned short f2bf(float f) {
    unsigned int u = __float_as_uint(f);
    unsigned int r = (u + 0x7fffu + ((u >> 16) & 1u)) >> 16;
    return (unsigned short)r;
}

static __device__ __forceinline__ float bf2f(unsigned short u) {
    return __uint_as_float((unsigned int)u << 16);
}

static __device__ __forceinline__ void gload_lds16(const void* g, void* l) {
    __builtin_amdgcn_global_load_lds(
        (const __attribute__((address_space(1))) unsigned int*)g,
        (__attribute__((address_space(3))) unsigned int*)l, 16, 0, 0);
}

// ---------------------------------------------------------------------------
// cvt_w: w_qkv fp32 [1536*512] -> bf16
// ---------------------------------------------------------------------------
__global__ __launch_bounds__(256) void cvt_w(const float* __restrict__ w,
                                             unsigned short* __restrict__ wb) {
    int i = (blockIdx.x * 256 + threadIdx.x) * 4;
    float4 v = *(const float4*)(w + i);
    __align__(8) unsigned short o[4] = {f2bf(v.x), f2bf(v.y), f2bf(v.z), f2bf(v.w)};
    *(uint2*)(wb + i) = *(const uint2*)o;
}

// ---------------------------------------------------------------------------
// transpose_x: x fp32 [b][512][4096] -> xT bf16 [b][4096][512]
// ---------------------------------------------------------------------------
__global__ __launch_bounds__(256) void transpose_x(const float* __restrict__ x,
                                                   unsigned short* __restrict__ xT) {
    __shared__ float tile[64][65];
    const int n0 = blockIdx.x * 64, d0 = blockIdx.y * 64, b = blockIdx.z;
    const float* xb = x + (size_t)b * D * N;
    unsigned short* xTb = xT + (size_t)b * N * KDIM;
    const int t = threadIdx.x;
    const int r = t >> 4, c4 = (t & 15) * 4;
#pragma unroll
    for (int i = 0; i < 4; ++i) {
        int row = r + i * 16;
        float4 v = *(const float4*)(xb + (size_t)(d0 + row) * N + n0 + c4);
        tile[row][c4 + 0] = v.x;
        tile[row][c4 + 1] = v.y;
        tile[row][c4 + 2] = v.z;
        tile[row][c4 + 3] = v.w;
    }
    __syncthreads();
#pragma unroll
    for (int pass = 0; pass < 2; ++pass) {
        int orow = (t >> 3) + pass * 32;
        int oc = (t & 7) * 8;
        __align__(16) unsigned short o[8];
#pragma unroll
        for (int e = 0; e < 8; ++e) o[e] = f2bf(tile[oc + e][orow]);
        *(uint4*)(xTb + (size_t)(n0 + orow) * KDIM + d0 + oc) = *(const uint4*)o;
    }
}

// ---------------------------------------------------------------------------
// shared GEMM core: 128x128 tile, BK=64, 4 waves, mfma_f32_16x16x32_bf16
// ---------------------------------------------------------------------------
#define GEMM_CORE(A_PTR, BT_PTR, ACC)                                              \
    __shared__ __align__(16) unsigned short As[128 * 64];                          \
    __shared__ __align__(16) unsigned short Bs[128 * 64];                          \
    const int t = threadIdx.x;                                                     \
    const int lane = t & 63;                                                       \
    const int wid = t >> 6;                                                        \
    const int wm = wid >> 1, wn = wid & 1;                                         \
    int prow[4], coff[4];                                                          \
    _Pragma("unroll") for (int i = 0; i < 4; ++i) {                                \
        int p = i * 4096 + t * 16;                                                 \
        int pr = p >> 7;                                                           \
        int pc = (p >> 4) & 7;                                                     \
        prow[i] = pr;                                                              \
        coff[i] = (pc ^ (pr & 7)) * 8;                                             \
    }                                                                              \
    int aoff[4][2], boff[4][2];                                                    \
    _Pragma("unroll") for (int m = 0; m < 4; ++m) {                                \
        int arow = wm * 64 + m * 16 + (lane & 15);                                 \
        int brow = wn * 64 + m * 16 + (lane & 15);                                 \
        _Pragma("unroll") for (int s = 0; s < 2; ++s) {                            \
            int chunk = s * 4 + (lane >> 4);                                       \
            aoff[m][s] = arow * 128 + ((chunk ^ (arow & 7)) << 4);                 \
            boff[m][s] = brow * 128 + ((chunk ^ (brow & 7)) << 4);                 \
        }                                                                          \
    }                                                                              \
    f32x4 ACC[4][4] = {};                                                          \
    for (int k0 = 0; k0 < KDIM; k0 += 64) {                                        \
        _Pragma("unroll") for (int i = 0; i < 4; ++i)                              \
            gload_lds16(A_PTR + (size_t)(row0 + prow[i]) * KDIM + k0 + coff[i],    \
                        (char*)As + i * 4096 + t * 16);                            \
        _Pragma("unroll") for (int i = 0; i < 4; ++i)                              \
            gload_lds16(BT_PTR + (size_t)(col0 + prow[i]) * KDIM + k0 + coff[i],   \
                        (char*)Bs + i * 4096 + t * 16);                            \
        __syncthreads();                                                           \
        bf16x8 af[4][2], bfr[4][2];                                                \
        _Pragma("unroll") for (int m = 0; m < 4; ++m)                              \
            _Pragma("unroll") for (int s = 0; s < 2; ++s) {                        \
                af[m][s] = *(const bf16x8*)((const char*)As + aoff[m][s]);         \
                bfr[m][s] = *(const bf16x8*)((const char*)Bs + boff[m][s]);        \
            }                                                                      \
        _Pragma("unroll") for (int s = 0; s < 2; ++s)                              \
            _Pragma("unroll") for (int m = 0; m < 4; ++m)                          \
                _Pragma("unroll") for (int n = 0; n < 4; ++n)                      \
                    ACC[m][n] = __builtin_amdgcn_mfma_f32_16x16x32_bf16(           \
                        af[m][s], bfr[n][s], ACC[m][n], 0, 0, 0);                  \
        __syncthreads();                                                           \
    }

// ---------------------------------------------------------------------------
// gemm_bt: fp32 output (final projection)
// ---------------------------------------------------------------------------
__global__ __launch_bounds__(256) void gemm_bt(const unsigned short* __restrict__ Aall, long long sA,
                                               const unsigned short* __restrict__ BTall, long long sBT,
                                               float* __restrict__ Call, long long sC) {
    const int b = blockIdx.z;
    const unsigned short* A = Aall + (size_t)b * sA;
    const unsigned short* BT = BTall + (size_t)b * sBT;
    float* C = Call + (size_t)b * sC;
    const int row0 = blockIdx.y * 128;
    const int col0 = blockIdx.x * 128;
    GEMM_CORE(A, BT, acc)
#pragma unroll
    for (int m = 0; m < 4; ++m) {
        int row_b = row0 + wm * 64 + m * 16 + (lane >> 4) * 4;
#pragma unroll
        for (int n = 0; n < 4; ++n) {
            int col = col0 + wn * 64 + n * 16 + (lane & 15);
#pragma unroll
            for (int r = 0; r < 4; ++r)
                C[(size_t)(row_b + r) * N + col] = acc[m][n][r];
        }
    }
}

// ---------------------------------------------------------------------------
// gemm_kv: k,v = w_qkv[512:1536] @ x -> bf16 kvb [b][1024][N]
// ---------------------------------------------------------------------------
__global__ __launch_bounds__(256) void gemm_kv(const unsigned short* __restrict__ Aw,
                                               const unsigned short* __restrict__ BTall,
                                               unsigned short* __restrict__ kvall) {
    const int b = blockIdx.z;
    const unsigned short* A = Aw;
    const unsigned short* BT = BTall + (size_t)b * N * KDIM;
    unsigned short* C = kvall + (size_t)b * 1024 * N;
    const int row0 = blockIdx.y * 128;
    const int col0 = blockIdx.x * 128;
    GEMM_CORE(A, BT, acc)
#pragma unroll
    for (int m = 0; m < 4; ++m) {
        int row_b = row0 + wm * 64 + m * 16 + (lane >> 4) * 4;
#pragma unroll
        for (int n = 0; n < 4; ++n) {
            int col = col0 + wn * 64 + n * 16 + (lane & 15);
#pragma unroll
            for (int r = 0; r < 4; ++r)
                C[(size_t)(row_b + r) * N + col] = f2bf(acc[m][n][r]);
        }
    }
}

// ---------------------------------------------------------------------------
// gemm_q_sm: q GEMM + fused softmax over d per head -> qT bf16 [b][n][512]
// ---------------------------------------------------------------------------
__global__ __launch_bounds__(256) void gemm_q_sm(const unsigned short* __restrict__ Aw,
                                                 const unsigned short* __restrict__ BTall,
                                                 unsigned short* __restrict__ qT) {
    const int b = blockIdx.z;
    const unsigned short* A = Aw;
    const unsigned short* BT = BTall + (size_t)b * N * KDIM;
    const int row0 = blockIdx.y * 128;
    const int col0 = blockIdx.x * 128;
    GEMM_CORE(A, BT, acc)
    const int h = blockIdx.y * 2 + wm;
    const int g = lane >> 4;
#pragma unroll
    for (int nf = 0; nf < 4; ++nf) {
        float mx = -1e30f;
#pragma unroll
        for (int m = 0; m < 4; ++m)
#pragma unroll
            for (int r = 0; r < 4; ++r) mx = fmaxf(mx, acc[m][nf][r]);
        mx = fmaxf(mx, __shfl_xor(mx, 16));
        mx = fmaxf(mx, __shfl_xor(mx, 32));
        float e[16];
        float s = 0.f;
#pragma unroll
        for (int m = 0; m < 4; ++m)
#pragma unroll
            for (int r = 0; r < 4; ++r) {
                e[m * 4 + r] = __expf(acc[m][nf][r] - mx);
                s += e[m * 4 + r];
            }
        s += __shfl_xor(s, 16);
        s += __shfl_xor(s, 32);
        float rs = SCALE / s;
        int n = col0 + wn * 64 + nf * 16 + (lane & 15);
        unsigned short* dst = qT + ((size_t)b * N + n) * KDIM + h * 64 + g * 4;
#pragma unroll
        for (int m = 0; m < 4; ++m) {
            __align__(8) unsigned short o4[4] = {f2bf(e[m * 4 + 0] * rs), f2bf(e[m * 4 + 1] * rs),
                                                 f2bf(e[m * 4 + 2] * rs), f2bf(e[m * 4 + 3] * rs)};
            *(uint2*)(dst + m * 16) = *(const uint2*)o4;
        }
    }
}

// ---------------------------------------------------------------------------
// kstat: per k-row max and 1/sum(exp) over n (bf16 input)
// ---------------------------------------------------------------------------
__global__ __launch_bounds__(256) void kstat(const unsigned short* __restrict__ kvb,
                                             float2* __restrict__ st) {
    const int row = blockIdx.x;
    const int b = blockIdx.y;
    const unsigned short* base = kvb + ((size_t)b * 1024 + row) * (size_t)N;
    const int t = threadIdx.x;
    __shared__ float redm[4];
    __shared__ float reds[4];

    __align__(16) unsigned short raw[16];
    *(uint4*)raw = *(const uint4*)(base + t * 16);
    *(uint4*)(raw + 8) = *(const uint4*)(base + t * 16 + 8);
    float v[16];
    float m = -1e30f;
#pragma unroll
    for (int i = 0; i < 16; ++i) {
        v[i] = bf2f(raw[i]);
        m = fmaxf(m, v[i]);
    }
#pragma unroll
    for (int off = 32; off; off >>= 1) m = fmaxf(m, __shfl_xor(m, off));
    const int wid = t >> 6, lane = t & 63;
    if (lane == 0) redm[wid] = m;
    __syncthreads();
    m = fmaxf(fmaxf(redm[0], redm[1]), fmaxf(redm[2], redm[3]));

    float s = 0.f;
#pragma unroll
    for (int i = 0; i < 16; ++i) s += __expf(v[i] - m);
#pragma unroll
    for (int off = 32; off; off >>= 1) s += __shfl_xor(s, off);
    if (lane == 0) reds[wid] = s;
    __syncthreads();
    if (t == 0) {
        s = reds[0] + reds[1] + reds[2] + reds[3];
        st[b * 512 + row] = make_float2(m, 1.f / s);
    }
}

// ---------------------------------------------------------------------------
// context_mfma: ctx[b,h,d,e] += sum_{n in chunk} exp(k[d,n]-m)*inv * v[e,n]
// MFMA form: per (b,h), M=64 (d), N=64 (e), K=4096 split in 8 chunks of 512.
// k reg-staged with exp applied (swizzled ds_write); v via global_load_lds
// with inverse-swizzled source. Wave wv owns d-rows wv*16..+15.
// ---------------------------------------------------------------------------
__global__ __launch_bounds__(256) void context_mfma(const unsigned short* __restrict__ kvb,
                                                    const float2* __restrict__ st,
                                                    float* __restrict__ ctx) {
    const int ch = blockIdx.x, h = blockIdx.y, b = blockIdx.z;
    const int K0 = ch * 512;
    const unsigned short* kbase = kvb + ((size_t)b * 1024 + h * DH) * (size_t)N + K0;
    const unsigned short* vbase = kvb + ((size_t)b * 1024 + 512 + h * DH) * (size_t)N + K0;

    __shared__ __align__(16) unsigned short Ks[64 * 64];
    __shared__ __align__(16) unsigned short Vs[64 * 64];

    const int t = threadIdx.x;
    const int lane = t & 63;
    const int wv = t >> 6;

    // k staging geometry: thread t handles row kr, cols kc..kc+15 (two 16B chunks)
    const int kr = t >> 2;
    const int kc = (t & 3) * 16;
    const float2 stv = st[b * 512 + h * DH + kr];
    const float mr = stv.x, ir = stv.y;
    // swizzled byte offsets of the two chunks
    const int kchunk0 = kc >> 3;  // 0,2,4,6
    const int kdst0 = kr * 128 + (((kchunk0 + 0) ^ (kr & 7)) << 4);
    const int kdst1 = kr * 128 + (((kchunk0 + 1) ^ (kr & 7)) << 4);

    // v staging geometry (gload_lds, inverse-swizzled source)
    int vrow[2], vcoff[2];
#pragma unroll
    for (int i = 0; i < 2; ++i) {
        int p = i * 4096 + t * 16;
        int pr = p >> 7;
        int pc = (p >> 4) & 7;
        vrow[i] = pr;
        vcoff[i] = (pc ^ (pr & 7)) * 8;
    }

    // fragment read offsets
    const int ar = wv * 16 + (lane & 15);
    int aoff[2], boff[4][2];
#pragma unroll
    for (int s = 0; s < 2; ++s) {
        int chunk = s * 4 + (lane >> 4);
        aoff[s] = ar * 128 + ((chunk ^ (ar & 7)) << 4);
#pragma unroll
        for (int nf = 0; nf < 4; ++nf) {
            int br = nf * 16 + (lane & 15);
            boff[nf][s] = br * 128 + ((chunk ^ (br & 7)) << 4);
        }
    }

    f32x4 acc[4] = {};

    for (int k0 = 0; k0 < 512; k0 += 64) {
        // stage v (async)
#pragma unroll
        for (int i = 0; i < 2; ++i)
            gload_lds16(vbase + (size_t)vrow[i] * N + k0 + vcoff[i],
                        (char*)Vs + i * 4096 + t * 16);
        // stage k with exp
        __align__(16) unsigned short raw[16];
        *(uint4*)raw = *(const uint4*)(kbase + (size_t)kr * N + k0 + kc);
        *(uint4*)(raw + 8) = *(const uint4*)(kbase + (size_t)kr * N + k0 + kc + 8);
        __align__(16) unsigned short o[16];
#pragma unroll
        for (int j = 0; j < 16; ++j) o[j] = f2bf(__expf(bf2f(raw[j]) - mr) * ir);
        *(uint4*)((char*)Ks + kdst0) = *(const uint4*)o;
        *(uint4*)((char*)Ks + kdst1) = *(const uint4*)(o + 8);
        __syncthreads();

        bf16x8 av[2], bv[4][2];
#pragma unroll
        for (int s = 0; s < 2; ++s) {
            av[s] = *(const bf16x8*)((const char*)Ks + aoff[s]);
#pragma unroll
            for (int nf = 0; nf < 4; ++nf)
                bv[nf][s] = *(const bf16x8*)((const char*)Vs + boff[nf][s]);
        }
#pragma unroll
        for (int s = 0; s < 2; ++s)
#pragma unroll
            for (int nf = 0; nf < 4; ++nf)
                acc[nf] = __builtin_amdgcn_mfma_f32_16x16x32_bf16(av[s], bv[nf][s], acc[nf], 0, 0, 0);
        __syncthreads();
    }

    float* cbase = ctx + ((size_t)(b * HEADS + h)) * DH * DH;
    const int drow = wv * 16 + (lane >> 4) * 4;
#pragma unroll
    for (int nf = 0; nf < 4; ++nf) {
        int e = nf * 16 + (lane & 15);
#pragma unroll
        for (int rr = 0; rr < 4; ++rr)
            atomicAdd(&cbase[(drow + rr) * DH + e], acc[nf][rr]);
    }
}

// ---------------------------------------------------------------------------
// fold_wout3: MFMA fold. Per (b,h): W2-slice[o][d] = sum_e w_out[o][h*64+e] *
// ctx[b,h,d,e].  M=512 (split in 4 o-tiles of 128), N=64, K=64.
// ---------------------------------------------------------------------------
__global__ __launch_bounds__(256) void fold_wout3(const float* __restrict__ w_out,
                                                  const float* __restrict__ ctx,
                                                  unsigned short* __restrict__ w2) {
    const int ot = blockIdx.x, h = blockIdx.y, b = blockIdx.z;
    __shared__ __align__(16) unsigned short As[128 * 64];
    __shared__ __align__(16) unsigned short Bs[64 * 64];
    const int t = threadIdx.x;
    const int lane = t & 63;
    const int wv = t >> 6;

#pragma unroll
    for (int i = 0; i < 8; ++i) {
        int lin = t + i * 256;
        int r = lin >> 4;
        int c4 = (lin & 15) * 4;
        float4 v = *(const float4*)(w_out + (size_t)(ot * 128 + r) * HID + h * 64 + c4);
        __align__(8) unsigned short o4[4] = {f2bf(v.x), f2bf(v.y), f2bf(v.z), f2bf(v.w)};
        int chunk = c4 >> 3;
        int off = (c4 & 7) * 2;
        *(uint2*)((char*)As + r * 128 + ((chunk ^ (r & 7)) << 4) + off) = *(const uint2*)o4;
    }
    const float* cb = ctx + ((size_t)(b * HEADS + h)) * DH * DH;
#pragma unroll
    for (int i = 0; i < 4; ++i) {
        int lin = t + i * 256;
        int r = lin >> 4;
        int c4 = (lin & 15) * 4;
        float4 v = *(const float4*)(cb + (size_t)r * DH + c4);
        __align__(8) unsigned short o4[4] = {f2bf(v.x), f2bf(v.y), f2bf(v.z), f2bf(v.w)};
        int chunk = c4 >> 3;
        int off = (c4 & 7) * 2;
        *(uint2*)((char*)Bs + r * 128 + ((chunk ^ (r & 7)) << 4) + off) = *(const uint2*)o4;
    }
    __syncthreads();

    f32x4 acc[2][4] = {};
#pragma unroll
    for (int s = 0; s < 2; ++s) {
        int chunk = s * 4 + (lane >> 4);
        bf16x8 bf[4];
#pragma unroll
        for (int nf = 0; nf < 4; ++nf) {
            int brow = nf * 16 + (lane & 15);
            bf[nf] = *(const bf16x8*)((const char*)Bs + brow * 128 + ((chunk ^ (brow & 7)) << 4));
        }
#pragma unroll
        for (int mm = 0; mm < 2; ++mm) {
            int arow = (wv * 2 + mm) * 16 + (lane & 15);
            bf16x8 a = *(const bf16x8*)((const char*)As + arow * 128 + ((chunk ^ (arow & 7)) << 4));
#pragma unroll
            for (int nf = 0; nf < 4; ++nf)
                acc[mm][nf] = __builtin_amdgcn_mfma_f32_16x16x32_bf16(a, bf[nf], acc[mm][nf], 0, 0, 0);
        }
    }

#pragma unroll
    for (int mm = 0; mm < 2; ++mm) {
        int o_base = ot * 128 + (wv * 2 + mm) * 16 + (lane >> 4) * 4;
#pragma unroll
        for (int nf = 0; nf < 4; ++nf) {
            int d = nf * 16 + (lane & 15);
#pragma unroll
            for (int rr = 0; rr < 4; ++rr)
                w2[((size_t)(b * D) + o_base + rr) * D + h * 64 + d] = f2bf(acc[mm][nf][rr]);
        }
    }
}

// ---------------------------------------------------------------------------
// rmsnorm2: 64-column x 512-row tile per block, grid (N/64, B) = 512 blocks
// ---------------------------------------------------------------------------
__global__ __launch_bounds__(256) void rmsnorm2(float* __restrict__ y,
                                                const float* __restrict__ b_out,
                                                const float* __restrict__ g) {
    const int b = blockIdx.y;
    const int n0 = blockIdx.x * 64;
    float* base = y + (size_t)b * D * N + n0;
    __shared__ float bsh[D], gsh[D];
    __shared__ float4 red[4][16];
    const int t = threadIdx.x;
    bsh[t] = b_out[t];
    bsh[t + 256] = b_out[t + 256];
    gsh[t] = g[t];
    gsh[t + 256] = g[t + 256];
    __syncthreads();

    const int cg = t & 15;
    const int rg = t >> 4;

    float4 ss = make_float4(0.f, 0.f, 0.f, 0.f);
#pragma unroll 8
    for (int i = 0; i < 32; ++i) {
        int o = rg + i * 16;
        float4 v = *(const float4*)(base + (size_t)o * N + cg * 4);
        float bo = bsh[o];
        v.x += bo; v.y += bo; v.z += bo; v.w += bo;
        ss.x += v.x * v.x;
        ss.y += v.y * v.y;
        ss.z += v.z * v.z;
        ss.w += v.w * v.w;
    }
    ss.x += __shfl_xor(ss.x, 16); ss.y += __shfl_xor(ss.y, 16);
    ss.z += __shfl_xor(ss.z, 16); ss.w += __shfl_xor(ss.w, 16);
    ss.x += __shfl_xor(ss.x, 32); ss.y += __shfl_xor(ss.y, 32);
    ss.z += __shfl_xor(ss.z, 32); ss.w += __shfl_xor(ss.w, 32);
    const int wave = t >> 6, lane = t & 63;
    if (lane < 16) red[wave][lane] = ss;
    __syncthreads();
    float4 s0 = red[0][cg], s1 = red[1][cg], s2 = red[2][cg], s3 = red[3][cg];
    float4 tot = make_float4(s0.x + s1.x + s2.x + s3.x, s0.y + s1.y + s2.y + s3.y,
                             s0.z + s1.z + s2.z + s3.z, s0.w + s1.w + s2.w + s3.w);
    float4 rinv;
    rinv.x = SQRT_D / fmaxf(sqrtf(tot.x), 1e-12f);
    rinv.y = SQRT_D / fmaxf(sqrtf(tot.y), 1e-12f);
    rinv.z = SQRT_D / fmaxf(sqrtf(tot.z), 1e-12f);
    rinv.w = SQRT_D / fmaxf(sqrtf(tot.w), 1e-12f);

#pragma unroll 8
    for (int i = 0; i < 32; ++i) {
        int o = rg + i * 16;
        float4 v = *(const float4*)(base + (size_t)o * N + cg * 4);
        float bo = bsh[o], go = gsh[o];
        v.x = (v.x + bo) * rinv.x * go;
        v.y = (v.y + bo) * rinv.y * go;
        v.z = (v.z + bo) * rinv.z * go;
        v.w = (v.w + bo) * rinv.w * go;
        *(float4*)(base + (size_t)o * N + cg * 4) = v;
    }
}

extern "C" void kernel_launch(void* const* d_in, const int* in_sizes, int n_in,
                              void* d_out, int out_size, void* d_ws, size_t ws_size,
                              hipStream_t stream) {
    const float* x = (const float*)d_in[0];
    const float* w_qkv = (const float*)d_in[1];
    const float* w_out = (const float*)d_in[2];
    const float* b_out = (const float*)d_in[3];
    const float* g = (const float*)d_in[4];
    float* out = (float*)d_out;

    // workspace layout
    unsigned short* kvb = (unsigned short*)d_ws;                // B*1024*N bf16 (64 MB)
    float* ctx = (float*)(kvb + (size_t)B * 1024 * N);          // 1 MB
    unsigned short* w2 = (unsigned short*)(ctx + (size_t)B * HEADS * DH * DH);  // 4 MB
    unsigned short* wqb = w2 + (size_t)B * D * D;               // 1.5 MB
    unsigned short* xT = wqb + (size_t)O3 * KDIM;               // 32 MB
    unsigned short* qT = xT + (size_t)B * N * KDIM;             // 32 MB
    float2* kst = (float2*)(qT + (size_t)B * N * KDIM);         // 32 KB

    hipMemsetAsync(ctx, 0, (size_t)B * HEADS * DH * DH * sizeof(float), stream);

    cvt_w<<<dim3(O3 * KDIM / 1024), 256, 0, stream>>>(w_qkv, wqb);
    transpose_x<<<dim3(N / 64, D / 64, B), 256, 0, stream>>>(x, xT);

    gemm_q_sm<<<dim3(N / 128, HID / 128, B), 256, 0, stream>>>(wqb, xT, qT);
    gemm_kv<<<dim3(N / 128, 8, B), 256, 0, stream>>>(wqb + (size_t)HID * KDIM, xT, kvb);

    kstat<<<dim3(HID, B), 256, 0, stream>>>(kvb, kst);
    context_mfma<<<dim3(8, HEADS, B), 256, 0, stream>>>(kvb, kst, ctx);
    fold_wout3<<<dim3(4, HEADS, B), 256, 0, stream>>>(w_out, ctx, w2);

    gemm_bt<<<dim3(N / 128, D / 128, B), 256, 0, stream>>>(
        w2, (long long)D * D, qT, (long long)N * KDIM, out, (long long)D * N);

    rmsnorm2<<<dim3(N / 64, B), 256, 0, stream>>>(out, b_out, g);
}